// Round 17
// baseline (223.223 us; speedup 1.0000x reference)
//
#include <hip/hip_runtime.h>
#include <hip/hip_bf16.h>
#include <math.h>

#define TSEQ 4096
#define DMODEL 768
#define DFF 3072
#define NHEADS 12
#define HDIM 64

typedef __attribute__((ext_vector_type(8))) short short8;
typedef __attribute__((ext_vector_type(4))) float f32x4;
typedef unsigned short ushort;
typedef unsigned int uint;

typedef __attribute__((address_space(1))) ushort as1_ushort;
typedef __attribute__((address_space(3))) ushort as3_ushort;

__device__ __forceinline__ void gl_lds16(const ushort* g, const ushort* l) {
    __builtin_amdgcn_global_load_lds((as1_ushort*)(uintptr_t)g,
                                     (as3_ushort*)(uint)(uintptr_t)l, 16, 0, 0);
}

__device__ __forceinline__ ushort f2bf(float f) {
    union { float f; unsigned i; } c; c.f = f;
    unsigned x = c.i;
    unsigned r = x + 0x7FFFu + ((x >> 16) & 1u);
    return (ushort)(r >> 16);
}
__device__ __forceinline__ float asf(uint u) {
    union { unsigned i; float f; } c; c.i = u; return c.f;
}
// tanh-form GELU
__device__ __forceinline__ float gelu_fast(float v) {
    float y = v * (0.7978845608f + 0.03567740814f * v * v);
    float u = exp2f(y * -2.8853900817779268f);
    float r;
    asm("v_rcp_f32 %0, %1" : "=v"(r) : "v"(1.f + u));
    return v * r;
}

// ---------------- LayerNorm * 0.5 -> bf16 ----------------
__global__ __launch_bounds__(256) void ln_half_kernel(
    const float* __restrict__ x, const float* __restrict__ g,
    const float* __restrict__ b, ushort* __restrict__ out)
{
    int row = blockIdx.x;
    const float* xr = x + (size_t)row * DMODEL;
    float v[3];
    float s = 0.f, s2 = 0.f;
    #pragma unroll
    for (int i = 0; i < 3; i++) {
        v[i] = xr[threadIdx.x + 256 * i];
        s += v[i]; s2 += v[i] * v[i];
    }
    #pragma unroll
    for (int m = 1; m < 64; m <<= 1) { s += __shfl_xor(s, m, 64); s2 += __shfl_xor(s2, m, 64); }
    __shared__ float ss[4], ss2[4];
    int wid = threadIdx.x >> 6;
    if ((threadIdx.x & 63) == 0) { ss[wid] = s; ss2[wid] = s2; }
    __syncthreads();
    s = ss[0] + ss[1] + ss[2] + ss[3];
    s2 = ss2[0] + ss2[1] + ss2[2] + ss2[3];
    float mu = s * (1.f / DMODEL);
    float var = s2 * (1.f / DMODEL) - mu * mu;
    float rs = rsqrtf(var + 1e-5f);
    #pragma unroll
    for (int i = 0; i < 3; i++) {
        int c = threadIdx.x + 256 * i;
        float h = (v[i] - mu) * rs * g[c] + b[c];
        out[(size_t)row * DMODEL + c] = f2bf(h * 0.5f);
    }
}

// ---------------- transpose + cast: in [K,N] f32 -> out [N,K] bf16 ----------------
__global__ __launch_bounds__(256) void transpose_cast_kernel(
    const float* __restrict__ in, ushort* __restrict__ out, int K, int N)
{
    __shared__ float tile[32][33];
    int k0 = blockIdx.x * 32, n0 = blockIdx.y * 32;
    int c = threadIdx.x & 31, r0 = threadIdx.x >> 5;
    #pragma unroll
    for (int i = 0; i < 4; i++) {
        int r = r0 + i * 8;
        tile[r][c] = in[(size_t)(k0 + r) * N + n0 + c];
    }
    __syncthreads();
    #pragma unroll
    for (int i = 0; i < 4; i++) {
        int r = r0 + i * 8;
        out[(size_t)(n0 + r) * K + k0 + c] = f2bf(tile[c][r]);
    }
}

// ---------------- GEMM BM=64 x BN=128 (block-count booster: QKV, FC1) ----------------
// 256 thr / 4 waves 2x2, each wave 32x64 (acc[2][4]).
// EPI 0: bias->bf16; 1: bias+GELU->bf16; 3: QKV fused V-transpose (bn>=1536 -> vTout).
template<int EPI>
__global__ __launch_bounds__(256) void gemm_6428_kernel(
    const ushort* __restrict__ A, const ushort* __restrict__ Bt,
    const float* __restrict__ bias,
    void* __restrict__ out, ushort* __restrict__ vTout, int M, int N, int K)
{
    __shared__ ushort As[2][64 * 32];
    __shared__ ushort Bs[2][128 * 32];
    int bm = blockIdx.x * 64, bn = blockIdx.y * 128;
    int tid = threadIdx.x;
    int wid = tid >> 6, lane = tid & 63;
    int wm = (wid >> 1) * 32, wn = (wid & 1) * 64;
    int lg = lane >> 4, lr = lane & 15;
    f32x4 acc[2][4] = {};

    // A staging: row tid>>2, XOR-unit source, lane-linear dest
    int sarow = tid >> 2;
    int saunit = (tid & 3) ^ (sarow & 3);
    const ushort* ga = A + (size_t)(bm + sarow) * K + saunit * 8;
    // B staging: 2 calls/thread; call j covers rows j*64 + wid*16 + (lane>>2)
    int sbrow0 = wid * 16 + (lane >> 2);
    int sbunit = (lane & 3) ^ ((lane >> 2) & 3);
    const ushort* gb0 = Bt + (size_t)(bn + sbrow0) * K + sbunit * 8;
    const ushort* gb1 = Bt + (size_t)(bn + 64 + sbrow0) * K + sbunit * 8;

    gl_lds16(ga,  &As[0][tid * 8]);
    gl_lds16(gb0, &Bs[0][tid * 8]);
    gl_lds16(gb1, &Bs[0][2048 + tid * 8]);

    int nt = K >> 5;
    for (int t = 0; t < nt; t++) {
        int cur = t & 1;
        __syncthreads();
        if (t + 1 < nt) {
            int k0 = (t + 1) << 5;
            int nb = cur ^ 1;
            gl_lds16(ga + k0,  &As[nb][tid * 8]);
            gl_lds16(gb0 + k0, &Bs[nb][tid * 8]);
            gl_lds16(gb1 + k0, &Bs[nb][2048 + tid * 8]);
        }
        short8 a[2], b[4];
        #pragma unroll
        for (int mi = 0; mi < 2; mi++) {
            int row = wm + mi * 16 + lr;
            a[mi] = *(const short8*)&As[cur][row * 32 + ((lg ^ (row & 3)) * 8)];
        }
        #pragma unroll
        for (int ni = 0; ni < 4; ni++) {
            int row = wn + ni * 16 + lr;
            b[ni] = *(const short8*)&Bs[cur][row * 32 + ((lg ^ (row & 3)) * 8)];
        }
        #pragma unroll
        for (int mi = 0; mi < 2; mi++)
            #pragma unroll
            for (int ni = 0; ni < 4; ni++)
                acc[mi][ni] = __builtin_amdgcn_mfma_f32_16x16x32_bf16(a[mi], b[ni], acc[mi][ni], 0, 0, 0);
    }

    #pragma unroll
    for (int mi = 0; mi < 2; mi++) {
        #pragma unroll
        for (int ni = 0; ni < 4; ni++) {
            int col = bn + wn + ni * 16 + lr;
            float bv = bias[col];
            if (EPI == 3 && bn >= 1536) {
                int row0 = bm + wm + mi * 16 + lg * 4;
                uint2 pk;
                pk.x = (uint)f2bf(acc[mi][ni][0] + bv) | ((uint)f2bf(acc[mi][ni][1] + bv) << 16);
                pk.y = (uint)f2bf(acc[mi][ni][2] + bv) | ((uint)f2bf(acc[mi][ni][3] + bv) << 16);
                *(uint2*)&vTout[(size_t)(col - 1536) * TSEQ + row0] = pk;
            } else {
                #pragma unroll
                for (int r = 0; r < 4; r++) {
                    int row = bm + wm + mi * 16 + lg * 4 + r;
                    float v = acc[mi][ni][r] + bv;
                    size_t idx = (size_t)row * N + col;
                    if (EPI == 1) {
                        ((ushort*)out)[idx] = f2bf(gelu_fast(v));
                    } else {
                        ((ushort*)out)[idx] = f2bf(v);
                    }
                }
            }
        }
    }
}

// ---------------- GEMM 64x64 (skinny-N: out-proj, FC2) ----------------
template<int EPI>
__global__ __launch_bounds__(256) void gemm_64_kernel(
    const ushort* __restrict__ A, const ushort* __restrict__ Bt,
    const float* __restrict__ bias, const float* __restrict__ res,
    void* __restrict__ out, int M, int N, int K)
{
    __shared__ ushort As[2][64 * 32];
    __shared__ ushort Bs[2][64 * 32];
    int bm = blockIdx.x * 64, bn = blockIdx.y * 64;
    int tid = threadIdx.x;
    int wid = tid >> 6, lane = tid & 63;
    int wm = (wid >> 1) * 32, wn = (wid & 1) * 32;
    int lg = lane >> 4, lr = lane & 15;
    int srow = tid >> 2;
    int sunit = (tid & 3) ^ (srow & 3);
    f32x4 acc[2][2] = {};

    const ushort* ga = A  + (size_t)(bm + srow) * K + sunit * 8;
    const ushort* gb = Bt + (size_t)(bn + srow) * K + sunit * 8;

    gl_lds16(ga, &As[0][tid * 8]);
    gl_lds16(gb, &Bs[0][tid * 8]);

    int nt = K >> 5;
    for (int t = 0; t < nt; t++) {
        int cur = t & 1;
        __syncthreads();
        if (t + 1 < nt) {
            int k0 = (t + 1) << 5;
            int nb = cur ^ 1;
            gl_lds16(ga + k0, &As[nb][tid * 8]);
            gl_lds16(gb + k0, &Bs[nb][tid * 8]);
        }
        short8 a[2], b[2];
        #pragma unroll
        for (int mi = 0; mi < 2; mi++) {
            int row = wm + mi * 16 + lr;
            a[mi] = *(const short8*)&As[cur][row * 32 + ((lg ^ (row & 3)) * 8)];
        }
        #pragma unroll
        for (int ni = 0; ni < 2; ni++) {
            int row = wn + ni * 16 + lr;
            b[ni] = *(const short8*)&Bs[cur][row * 32 + ((lg ^ (row & 3)) * 8)];
        }
        #pragma unroll
        for (int mi = 0; mi < 2; mi++)
            #pragma unroll
            for (int ni = 0; ni < 2; ni++)
                acc[mi][ni] = __builtin_amdgcn_mfma_f32_16x16x32_bf16(a[mi], b[ni], acc[mi][ni], 0, 0, 0);
    }

    #pragma unroll
    for (int mi = 0; mi < 2; mi++) {
        #pragma unroll
        for (int ni = 0; ni < 2; ni++) {
            int col = bn + wn + ni * 16 + lr;
            float bv = bias[col];
            #pragma unroll
            for (int r = 0; r < 4; r++) {
                int row = bm + wm + mi * 16 + lg * 4 + r;
                float v = acc[mi][ni][r] + bv;
                size_t idx = (size_t)row * N + col;
                if (EPI == 0) {
                    ((ushort*)out)[idx] = f2bf(v);
                } else if (EPI == 1) {
                    ((ushort*)out)[idx] = f2bf(gelu_fast(v));
                } else {
                    ((float*)out)[idx] = v + res[idx];
                }
            }
        }
    }
}

// ---------------- flash attention (split-K x4, QBLK=256, 52KB LDS, XCD-local KV) ----------------
__global__ __launch_bounds__(512) void attn_kernel(
    const ushort* __restrict__ qkv, const ushort* __restrict__ vT,
    ushort* __restrict__ Opart, float* __restrict__ ml)
{
    int combo = blockIdx.x % 48;
    int qblk  = blockIdx.x / 48;
    int h     = combo >> 2;
    int split = combo & 3;
    __shared__ ushort smem[16384 + 256 * 40];    // K/V dbuf (32KB) + P scratch (20KB)
    ushort* Ps = smem + 16384;
    int tid = threadIdx.x, wid = tid >> 6, lane = tid & 63;
    int lg = lane >> 4, lr = lane & 15;
    const float C1 = 0.18033688011112042f;   // 0.125 * log2(e)
    const float KC = 12.0f * C1;
    int x7 = lr & 7;

    { // stage Q: dest-XOR swizzled LDS, linear global source
        int row = tid >> 1;
        int u0 = (tid & 1) * 4;
        int r7 = row & 7;
        const ushort* src = qkv + (size_t)(qblk * 256 + row) * 2304 + h * HDIM;
        #pragma unroll
        for (int i = 0; i < 4; i++) {
            int u = u0 + i;
            *(short8*)&smem[row * 64 + ((u ^ r7) * 8)] = *(const short8*)(src + (size_t)(u * 8));
        }
    }
    int q0row = (wid * 32 + lr) * 64;
    int q1row = q0row + 16 * 64;
    short8 qa0 = *(const short8*)&smem[q0row + (lg ^ x7) * 8];
    short8 qa1 = *(const short8*)&smem[q0row + ((4 + lg) ^ x7) * 8];
    short8 qb0 = *(const short8*)&smem[q1row + (lg ^ x7) * 8];
    short8 qb1 = *(const short8*)&smem[q1row + ((4 + lg) ^ x7) * 8];
    __syncthreads();

    short8 vone;
    #pragma unroll
    for (int i = 0; i < 8; i++) vone[i] = (short)0x3F80;

    int krow = tid >> 3;
    int kunit = (tid & 7) ^ (krow & 7);
    const ushort* kg = qkv + (size_t)(split * 1024 + krow) * 2304 + DMODEL + h * HDIM + kunit * 8;
    const ushort* vgp = vT + (size_t)(h * HDIM + krow) * TSEQ + split * 1024 + kunit * 8;

    gl_lds16(kg, &smem[tid * 8]);
    gl_lds16(vgp, &smem[8192 + tid * 8]);
    kg += 64 * 2304;
    vgp += 64;

    f32x4 o0[4] = {}, o1[4] = {};
    f32x4 s0sum = {}, s1sum = {};
    const int NT = 16;
    int prow0 = (wid * 32 + lr) * 40;
    int prow1 = prow0 + 16 * 40;

    for (int kt = 0; kt < NT; kt++) {
        int cur = kt & 1, nb = cur ^ 1;
        __syncthreads();
        if (kt + 1 < NT) {
            gl_lds16(kg, &smem[nb * 4096 + tid * 8]);
            gl_lds16(vgp, &smem[8192 + nb * 4096 + tid * 8]);
            kg += 64 * 2304;
            vgp += 64;
        }
        const ushort* kb = &smem[cur * 4096];
        const ushort* vb = &smem[8192 + cur * 4096];

        f32x4 st0[4] = {}, st1[4] = {};
        __builtin_amdgcn_s_setprio(1);
        #pragma unroll
        for (int ki = 0; ki < 4; ki++) {
            const ushort* kr = &kb[(ki * 16 + lr) * 64];
            short8 k0 = *(const short8*)&kr[(lg ^ x7) * 8];
            short8 k1 = *(const short8*)&kr[((4 + lg) ^ x7) * 8];
            st0[ki] = __builtin_amdgcn_mfma_f32_16x16x32_bf16(k0, qa0, st0[ki], 0, 0, 0);
            st0[ki] = __builtin_amdgcn_mfma_f32_16x16x32_bf16(k1, qa1, st0[ki], 0, 0, 0);
            st1[ki] = __builtin_amdgcn_mfma_f32_16x16x32_bf16(k0, qb0, st1[ki], 0, 0, 0);
            st1[ki] = __builtin_amdgcn_mfma_f32_16x16x32_bf16(k1, qb1, st1[ki], 0, 0, 0);
        }
        __builtin_amdgcn_s_setprio(0);

        uint2 c0[4], c1[4];
        #pragma unroll
        for (int ki = 0; ki < 4; ki++) {
            #pragma unroll
            for (int r = 0; r < 4; r++) st0[ki][r] = exp2f(st0[ki][r] * C1 - KC);
            asm("v_cvt_pk_bf16_f32 %0, %1, %2" : "=v"(c0[ki].x) : "v"(st0[ki][0]), "v"(st0[ki][1]));
            asm("v_cvt_pk_bf16_f32 %0, %1, %2" : "=v"(c0[ki].y) : "v"(st0[ki][2]), "v"(st0[ki][3]));
        }
        #pragma unroll
        for (int ki = 0; ki < 4; ki++) {
            #pragma unroll
            for (int r = 0; r < 4; r++) st1[ki][r] = exp2f(st1[ki][r] * C1 - KC);
            asm("v_cvt_pk_bf16_f32 %0, %1, %2" : "=v"(c1[ki].x) : "v"(st1[ki][0]), "v"(st1[ki][1]));
            asm("v_cvt_pk_bf16_f32 %0, %1, %2" : "=v"(c1[ki].y) : "v"(st1[ki][2]), "v"(st1[ki][3]));
        }

        *(uint2*)&Ps[prow0 + lg * 4]      = c0[0];
        *(uint2*)&Ps[prow0 + 16 + lg * 4] = c0[1];
        *(uint2*)&Ps[prow1 + lg * 4]      = c1[0];
        *(uint2*)&Ps[prow1 + 16 + lg * 4] = c1[1];
        {
            short8 pa00 = *(const short8*)&Ps[prow0 + lg * 8];
            short8 pa10 = *(const short8*)&Ps[prow1 + lg * 8];
            __builtin_amdgcn_s_setprio(1);
            s0sum = __builtin_amdgcn_mfma_f32_16x16x32_bf16(pa00, vone, s0sum, 0, 0, 0);
            s1sum = __builtin_amdgcn_mfma_f32_16x16x32_bf16(pa10, vone, s1sum, 0, 0, 0);
            #pragma unroll
            for (int ni = 0; ni < 4; ni++) {
                short8 b0 = *(const short8*)&vb[(ni * 16 + lr) * 64 + (lg ^ x7) * 8];
                o0[ni] = __builtin_amdgcn_mfma_f32_16x16x32_bf16(pa00, b0, o0[ni], 0, 0, 0);
                o1[ni] = __builtin_amdgcn_mfma_f32_16x16x32_bf16(pa10, b0, o1[ni], 0, 0, 0);
            }
            __builtin_amdgcn_s_setprio(0);
        }
        *(uint2*)&Ps[prow0 + lg * 4]      = c0[2];
        *(uint2*)&Ps[prow0 + 16 + lg * 4] = c0[3];
        *(uint2*)&Ps[prow1 + lg * 4]      = c1[2];
        *(uint2*)&Ps[prow1 + 16 + lg * 4] = c1[3];
        {
            short8 pa01 = *(const short8*)&Ps[prow0 + lg * 8];
            short8 pa11 = *(const short8*)&Ps[prow1 + lg * 8];
            __builtin_amdgcn_s_setprio(1);
            s0sum = __builtin_amdgcn_mfma_f32_16x16x32_bf16(pa01, vone, s0sum, 0, 0, 0);
            s1sum = __builtin_amdgcn_mfma_f32_16x16x32_bf16(pa11, vone, s1sum, 0, 0, 0);
            #pragma unroll
            for (int ni = 0; ni < 4; ni++) {
                short8 b1 = *(const short8*)&vb[(ni * 16 + lr) * 64 + ((4 + lg) ^ x7) * 8];
                o0[ni] = __builtin_amdgcn_mfma_f32_16x16x32_bf16(pa01, b1, o0[ni], 0, 0, 0);
                o1[ni] = __builtin_amdgcn_mfma_f32_16x16x32_bf16(pa11, b1, o1[ni], 0, 0, 0);
            }
            __builtin_amdgcn_s_setprio(0);
        }
    }

    if (lr == 0) {
        #pragma unroll
        for (int r = 0; r < 4; r++) {
            int q0 = qblk * 256 + wid * 32 + lg * 4 + r;
            ml[((size_t)split * NHEADS + h) * TSEQ + q0]      = s0sum[r];
            ml[((size_t)split * NHEADS + h) * TSEQ + q0 + 16] = s1sum[r];
        }
    }
    #pragma unroll
    for (int ni = 0; ni < 4; ni++)
        #pragma unroll
        for (int r = 0; r < 4; r++) {
            int q0 = qblk * 256 + wid * 32 + lg * 4 + r;
            int dcol = ni * 16 + lr;
            Opart[((size_t)split * TSEQ + q0) * DMODEL + h * HDIM + dcol]      = f2bf(o0[ni][r]);
            Opart[((size_t)split * TSEQ + q0 + 16) * DMODEL + h * HDIM + dcol] = f2bf(o1[ni][r]);
        }
}

// ---------------- combine 4 split partials -> attn bf16 ----------------
__global__ __launch_bounds__(256) void attn_combine_kernel(
    const ushort* __restrict__ Opart, const float* __restrict__ ml,
    ushort* __restrict__ attnb)
{
    int gid = blockIdx.x * 256 + threadIdx.x;
    int q = gid / 192;
    int c = (gid - q * 192) * 4;
    int hh = c >> 6;
    float denom = 0.f;
    float a0 = 0.f, a1 = 0.f, a2 = 0.f, a3 = 0.f;
    #pragma unroll
    for (int s = 0; s < 4; s++) {
        denom += ml[((size_t)s * NHEADS + hh) * TSEQ + q];
        uint2 ov = *(const uint2*)&Opart[((size_t)s * TSEQ + q) * DMODEL + c];
        a0 += asf(ov.x << 16);
        a1 += asf(ov.x & 0xFFFF0000u);
        a2 += asf(ov.y << 16);
        a3 += asf(ov.y & 0xFFFF0000u);
    }
    float rd = 1.f / denom;
    uint2 stv;
    stv.x = (uint)f2bf(a0 * rd) | ((uint)f2bf(a1 * rd) << 16);
    stv.y = (uint)f2bf(a2 * rd) | ((uint)f2bf(a3 * rd) << 16);
    *(uint2*)&attnb[(size_t)q * DMODEL + c] = stv;
}

// ---------------- host launch ----------------
extern "C" void kernel_launch(void* const* d_in, const int* in_sizes, int n_in,
                              void* d_out, int out_size, void* d_ws, size_t ws_size,
                              hipStream_t stream)
{
    const float* x      = (const float*)d_in[0];
    const float* ln1_g  = (const float*)d_in[1];
    const float* ln1_b  = (const float*)d_in[2];
    const float* ln2_g  = (const float*)d_in[3];
    const float* ln2_b  = (const float*)d_in[4];
    const float* qkv_w  = (const float*)d_in[5];
    const float* qkv_b  = (const float*)d_in[6];
    const float* out_w  = (const float*)d_in[7];
    const float* out_b  = (const float*)d_in[8];
    const float* fc1_w  = (const float*)d_in[9];
    const float* fc1_b  = (const float*)d_in[10];
    const float* fc2_w  = (const float*)d_in[11];
    const float* fc2_b  = (const float*)d_in[12];
    (void)in_sizes; (void)n_in; (void)out_size; (void)ws_size;

    char* p = (char*)d_ws;
    ushort* qkvb  = (ushort*)p;                 p += (size_t)TSEQ * DFF * 2;          // also gelu-out
    ushort* hb    = (ushort*)p;                 p += (size_t)TSEQ * DMODEL * 2;
    ushort* attnb = (ushort*)p;                 p += (size_t)TSEQ * DMODEL * 2;
    float*  x2    = (float*)p;                  p += (size_t)TSEQ * DMODEL * 4;
    ushort* qkv_wT = (ushort*)p;                p += (size_t)(3 * DMODEL) * DMODEL * 2;
    ushort* out_wT = (ushort*)p;                p += (size_t)DMODEL * DMODEL * 2;
    ushort* fc1_wT = (ushort*)p;                p += (size_t)DFF * DMODEL * 2;
    ushort* fc2_wT = (ushort*)p;                p += (size_t)DMODEL * DFF * 2;
    ushort* Opart  = (ushort*)p;                p += (size_t)4 * TSEQ * DMODEL * 2;
    float*  mlbuf  = (float*)p;                 p += (size_t)4 * NHEADS * TSEQ * 4;
    ushort* vTb    = (ushort*)p;                p += (size_t)DMODEL * TSEQ * 2;
    ushort* gb = qkvb;

    transpose_cast_kernel<<<dim3(DMODEL / 32, 3 * DMODEL / 32), 256, 0, stream>>>(qkv_w, qkv_wT, DMODEL, 3 * DMODEL);
    transpose_cast_kernel<<<dim3(DMODEL / 32, DMODEL / 32), 256, 0, stream>>>(out_w, out_wT, DMODEL, DMODEL);
    transpose_cast_kernel<<<dim3(DMODEL / 32, DFF / 32), 256, 0, stream>>>(fc1_w, fc1_wT, DMODEL, DFF);
    transpose_cast_kernel<<<dim3(DFF / 32, DMODEL / 32), 256, 0, stream>>>(fc2_w, fc2_wT, DFF, DMODEL);

    ln_half_kernel<<<TSEQ, 256, 0, stream>>>(x, ln1_g, ln1_b, hb);
    // QKV GEMM (64x128 tiles, fused V-transpose epilogue)
    gemm_6428_kernel<3><<<dim3(TSEQ / 64, 3 * DMODEL / 128), 256, 0, stream>>>(
        hb, qkv_wT, qkv_b, qkvb, vTb, TSEQ, 3 * DMODEL, DMODEL);
    attn_kernel<<<dim3((TSEQ / 256) * NHEADS * 4), 512, 0, stream>>>(qkvb, vTb, Opart, mlbuf);
    attn_combine_kernel<<<(TSEQ * DMODEL / 4) / 256, 256, 0, stream>>>(Opart, mlbuf, attnb);
    gemm_64_kernel<2><<<dim3(TSEQ / 64, DMODEL / 64), 256, 0, stream>>>(
        attnb, out_wT, out_b, x, x2, TSEQ, DMODEL, DMODEL);
    ln_half_kernel<<<TSEQ, 256, 0, stream>>>(x2, ln2_g, ln2_b, hb);
    // FC1 (64x128 tiles, GELU epilogue)
    gemm_6428_kernel<1><<<dim3(TSEQ / 64, DFF / 128), 256, 0, stream>>>(
        hb, fc1_wT, fc1_b, gb, nullptr, TSEQ, DFF, DMODEL);
    gemm_64_kernel<2><<<dim3(TSEQ / 64, DMODEL / 64), 256, 0, stream>>>(
        gb, fc2_wT, fc2_b, x2, (float*)d_out, TSEQ, DMODEL, DFF);
}

// Round 18
// 205.802 us; speedup vs baseline: 1.0846x; 1.0846x over previous
//
#include <hip/hip_runtime.h>
#include <hip/hip_bf16.h>
#include <math.h>

#define TSEQ 4096
#define DMODEL 768
#define DFF 3072
#define NHEADS 12
#define HDIM 64

typedef __attribute__((ext_vector_type(8))) short short8;
typedef __attribute__((ext_vector_type(4))) float f32x4;
typedef unsigned short ushort;
typedef unsigned int uint;

typedef __attribute__((address_space(1))) ushort as1_ushort;
typedef __attribute__((address_space(3))) ushort as3_ushort;

__device__ __forceinline__ void gl_lds16(const ushort* g, const ushort* l) {
    __builtin_amdgcn_global_load_lds((as1_ushort*)(uintptr_t)g,
                                     (as3_ushort*)(uint)(uintptr_t)l, 16, 0, 0);
}

__device__ __forceinline__ ushort f2bf(float f) {
    union { float f; unsigned i; } c; c.f = f;
    unsigned x = c.i;
    unsigned r = x + 0x7FFFu + ((x >> 16) & 1u);
    return (ushort)(r >> 16);
}
__device__ __forceinline__ float asf(uint u) {
    union { unsigned i; float f; } c; c.i = u; return c.f;
}
// tanh-form GELU
__device__ __forceinline__ float gelu_fast(float v) {
    float y = v * (0.7978845608f + 0.03567740814f * v * v);
    float u = exp2f(y * -2.8853900817779268f);
    float r;
    asm("v_rcp_f32 %0, %1" : "=v"(r) : "v"(1.f + u));
    return v * r;
}

// ---------------- LayerNorm * 0.5 -> bf16 ----------------
__global__ __launch_bounds__(256) void ln_half_kernel(
    const float* __restrict__ x, const float* __restrict__ g,
    const float* __restrict__ b, ushort* __restrict__ out)
{
    int row = blockIdx.x;
    const float* xr = x + (size_t)row * DMODEL;
    float v[3];
    float s = 0.f, s2 = 0.f;
    #pragma unroll
    for (int i = 0; i < 3; i++) {
        v[i] = xr[threadIdx.x + 256 * i];
        s += v[i]; s2 += v[i] * v[i];
    }
    #pragma unroll
    for (int m = 1; m < 64; m <<= 1) { s += __shfl_xor(s, m, 64); s2 += __shfl_xor(s2, m, 64); }
    __shared__ float ss[4], ss2[4];
    int wid = threadIdx.x >> 6;
    if ((threadIdx.x & 63) == 0) { ss[wid] = s; ss2[wid] = s2; }
    __syncthreads();
    s = ss[0] + ss[1] + ss[2] + ss[3];
    s2 = ss2[0] + ss2[1] + ss2[2] + ss2[3];
    float mu = s * (1.f / DMODEL);
    float var = s2 * (1.f / DMODEL) - mu * mu;
    float rs = rsqrtf(var + 1e-5f);
    #pragma unroll
    for (int i = 0; i < 3; i++) {
        int c = threadIdx.x + 256 * i;
        float h = (v[i] - mu) * rs * g[c] + b[c];
        out[(size_t)row * DMODEL + c] = f2bf(h * 0.5f);
    }
}

// ---------------- merged weight transpose+cast: all 4 weights in one launch ----------------
// block ranges: [0,1728) qkv_w 768x2304 ; [1728,2304) out_w 768x768 ;
//               [2304,4608) fc1_w 768x3072 ; [4608,6912) fc2_w 3072x768
__global__ __launch_bounds__(256) void transpose_all_kernel(
    const float* __restrict__ qkv_w, const float* __restrict__ out_w,
    const float* __restrict__ fc1_w, const float* __restrict__ fc2_w,
    ushort* __restrict__ qkv_wT, ushort* __restrict__ out_wT,
    ushort* __restrict__ fc1_wT, ushort* __restrict__ fc2_wT)
{
    int bid = blockIdx.x;
    const float* in; ushort* out; int K, N, tile_id;
    if (bid < 1728)      { in = qkv_w; out = qkv_wT; K = 768;  N = 2304; tile_id = bid; }
    else if (bid < 2304) { in = out_w; out = out_wT; K = 768;  N = 768;  tile_id = bid - 1728; }
    else if (bid < 4608) { in = fc1_w; out = fc1_wT; K = 768;  N = 3072; tile_id = bid - 2304; }
    else                 { in = fc2_w; out = fc2_wT; K = 3072; N = 768;  tile_id = bid - 4608; }
    int nx = K >> 5;
    int k0 = (tile_id % nx) * 32, n0 = (tile_id / nx) * 32;

    __shared__ float tile[32][33];
    int c = threadIdx.x & 31, r0 = threadIdx.x >> 5;
    #pragma unroll
    for (int i = 0; i < 4; i++) {
        int r = r0 + i * 8;
        tile[r][c] = in[(size_t)(k0 + r) * N + n0 + c];
    }
    __syncthreads();
    #pragma unroll
    for (int i = 0; i < 4; i++) {
        int r = r0 + i * 8;
        out[(size_t)(n0 + r) * K + k0 + c] = f2bf(tile[c][r]);
    }
}

// ---------------- GEMM BN=128 (EPI 0: bias->bf16; 1: bias+GELU->bf16; 2: bias+res->f32;
//                  3: QKV fused — V-range columns (bn>=1536) written TRANSPOSED to vTout) --------
template<int EPI>
__global__ __launch_bounds__(256) void gemm_kernel(
    const ushort* __restrict__ A, const ushort* __restrict__ Bt,
    const float* __restrict__ bias, const float* __restrict__ res,
    void* __restrict__ out, ushort* __restrict__ vTout, int M, int N, int K)
{
    __shared__ ushort As[2][128 * 32];
    __shared__ ushort Bs[2][128 * 32];
    int bm = blockIdx.x * 128, bn = blockIdx.y * 128;
    int tid = threadIdx.x;
    int wid = tid >> 6, lane = tid & 63;
    int wm = (wid >> 1) * 64, wn = (wid & 1) * 64;
    int lg = lane >> 4, lr = lane & 15;
    int srow = lane >> 2, scol = (lane & 3) * 8;
    f32x4 acc[4][4] = {};

    const ushort* ga0 = A  + (size_t)(bm + wid * 16 + srow) * K + scol;
    const ushort* ga1 = A  + (size_t)(bm + 64 + wid * 16 + srow) * K + scol;
    const ushort* gb0 = Bt + (size_t)(bn + wid * 16 + srow) * K + scol;
    const ushort* gb1 = Bt + (size_t)(bn + 64 + wid * 16 + srow) * K + scol;

    gl_lds16(ga0, &As[0][wid * 512]);
    gl_lds16(ga1, &As[0][2048 + wid * 512]);
    gl_lds16(gb0, &Bs[0][wid * 512]);
    gl_lds16(gb1, &Bs[0][2048 + wid * 512]);

    int nt = K >> 5;
    for (int t = 0; t < nt; t++) {
        int cur = t & 1;
        __syncthreads();
        if (t + 1 < nt) {
            int k0 = (t + 1) << 5;
            int nb = cur ^ 1;
            gl_lds16(ga0 + k0, &As[nb][wid * 512]);
            gl_lds16(ga1 + k0, &As[nb][2048 + wid * 512]);
            gl_lds16(gb0 + k0, &Bs[nb][wid * 512]);
            gl_lds16(gb1 + k0, &Bs[nb][2048 + wid * 512]);
        }
        short8 a[4], b[4];
        #pragma unroll
        for (int mi = 0; mi < 4; mi++) a[mi] = *(const short8*)&As[cur][(wm + mi * 16 + lr) * 32 + lg * 8];
        #pragma unroll
        for (int ni = 0; ni < 4; ni++) b[ni] = *(const short8*)&Bs[cur][(wn + ni * 16 + lr) * 32 + lg * 8];
        #pragma unroll
        for (int mi = 0; mi < 4; mi++)
            #pragma unroll
            for (int ni = 0; ni < 4; ni++)
                acc[mi][ni] = __builtin_amdgcn_mfma_f32_16x16x32_bf16(a[mi], b[ni], acc[mi][ni], 0, 0, 0);
    }

    #pragma unroll
    for (int mi = 0; mi < 4; mi++) {
        #pragma unroll
        for (int ni = 0; ni < 4; ni++) {
            int col = bn + wn + ni * 16 + lr;
            float bv = bias[col];
            if (EPI == 3 && bn >= 1536) {
                // V columns -> vT[col-1536][row], 4 consecutive rows packed (8B store)
                int row0 = bm + wm + mi * 16 + lg * 4;
                uint2 pk;
                pk.x = (uint)f2bf(acc[mi][ni][0] + bv) | ((uint)f2bf(acc[mi][ni][1] + bv) << 16);
                pk.y = (uint)f2bf(acc[mi][ni][2] + bv) | ((uint)f2bf(acc[mi][ni][3] + bv) << 16);
                *(uint2*)&vTout[(size_t)(col - 1536) * TSEQ + row0] = pk;
            } else {
                #pragma unroll
                for (int r = 0; r < 4; r++) {
                    int row = bm + wm + mi * 16 + lg * 4 + r;
                    float v = acc[mi][ni][r] + bv;
                    size_t idx = (size_t)row * N + col;
                    if (EPI == 1) {
                        ((ushort*)out)[idx] = f2bf(gelu_fast(v));
                    } else if (EPI == 2) {
                        ((float*)out)[idx] = v + res[idx];
                    } else {
                        ((ushort*)out)[idx] = f2bf(v);
                    }
                }
            }
        }
    }
}

// ---------------- GEMM 64x64 (skinny-N: out-proj, FC2) ----------------
template<int EPI>
__global__ __launch_bounds__(256) void gemm_64_kernel(
    const ushort* __restrict__ A, const ushort* __restrict__ Bt,
    const float* __restrict__ bias, const float* __restrict__ res,
    void* __restrict__ out, int M, int N, int K)
{
    __shared__ ushort As[2][64 * 32];
    __shared__ ushort Bs[2][64 * 32];
    int bm = blockIdx.x * 64, bn = blockIdx.y * 64;
    int tid = threadIdx.x;
    int wid = tid >> 6, lane = tid & 63;
    int wm = (wid >> 1) * 32, wn = (wid & 1) * 32;
    int lg = lane >> 4, lr = lane & 15;
    int srow = tid >> 2;
    int sunit = (tid & 3) ^ (srow & 3);
    f32x4 acc[2][2] = {};

    const ushort* ga = A  + (size_t)(bm + srow) * K + sunit * 8;
    const ushort* gb = Bt + (size_t)(bn + srow) * K + sunit * 8;

    gl_lds16(ga, &As[0][tid * 8]);
    gl_lds16(gb, &Bs[0][tid * 8]);

    int nt = K >> 5;
    for (int t = 0; t < nt; t++) {
        int cur = t & 1;
        __syncthreads();
        if (t + 1 < nt) {
            int k0 = (t + 1) << 5;
            int nb = cur ^ 1;
            gl_lds16(ga + k0, &As[nb][tid * 8]);
            gl_lds16(gb + k0, &Bs[nb][tid * 8]);
        }
        short8 a[2], b[2];
        #pragma unroll
        for (int mi = 0; mi < 2; mi++) {
            int row = wm + mi * 16 + lr;
            a[mi] = *(const short8*)&As[cur][row * 32 + ((lg ^ (row & 3)) * 8)];
        }
        #pragma unroll
        for (int ni = 0; ni < 2; ni++) {
            int row = wn + ni * 16 + lr;
            b[ni] = *(const short8*)&Bs[cur][row * 32 + ((lg ^ (row & 3)) * 8)];
        }
        #pragma unroll
        for (int mi = 0; mi < 2; mi++)
            #pragma unroll
            for (int ni = 0; ni < 2; ni++)
                acc[mi][ni] = __builtin_amdgcn_mfma_f32_16x16x32_bf16(a[mi], b[ni], acc[mi][ni], 0, 0, 0);
    }

    #pragma unroll
    for (int mi = 0; mi < 2; mi++) {
        #pragma unroll
        for (int ni = 0; ni < 2; ni++) {
            int col = bn + wn + ni * 16 + lr;
            float bv = bias[col];
            #pragma unroll
            for (int r = 0; r < 4; r++) {
                int row = bm + wm + mi * 16 + lg * 4 + r;
                float v = acc[mi][ni][r] + bv;
                size_t idx = (size_t)row * N + col;
                if (EPI == 0) {
                    ((ushort*)out)[idx] = f2bf(v);
                } else if (EPI == 1) {
                    ((ushort*)out)[idx] = f2bf(gelu_fast(v));
                } else {
                    ((float*)out)[idx] = v + res[idx];
                }
            }
        }
    }
}

// ---------------- flash attention (split-K x4, QBLK=256, 52KB LDS, XCD-local KV) ----------------
__global__ __launch_bounds__(512) void attn_kernel(
    const ushort* __restrict__ qkv, const ushort* __restrict__ vT,
    ushort* __restrict__ Opart, float* __restrict__ ml)
{
    int combo = blockIdx.x % 48;
    int qblk  = blockIdx.x / 48;
    int h     = combo >> 2;
    int split = combo & 3;
    __shared__ ushort smem[16384 + 256 * 40];    // K/V dbuf (32KB) + P scratch (20KB)
    ushort* Ps = smem + 16384;
    int tid = threadIdx.x, wid = tid >> 6, lane = tid & 63;
    int lg = lane >> 4, lr = lane & 15;
    const float C1 = 0.18033688011112042f;   // 0.125 * log2(e)
    const float KC = 12.0f * C1;
    int x7 = lr & 7;

    { // stage Q: dest-XOR swizzled LDS, linear global source
        int row = tid >> 1;
        int u0 = (tid & 1) * 4;
        int r7 = row & 7;
        const ushort* src = qkv + (size_t)(qblk * 256 + row) * 2304 + h * HDIM;
        #pragma unroll
        for (int i = 0; i < 4; i++) {
            int u = u0 + i;
            *(short8*)&smem[row * 64 + ((u ^ r7) * 8)] = *(const short8*)(src + (size_t)(u * 8));
        }
    }
    int q0row = (wid * 32 + lr) * 64;
    int q1row = q0row + 16 * 64;
    short8 qa0 = *(const short8*)&smem[q0row + (lg ^ x7) * 8];
    short8 qa1 = *(const short8*)&smem[q0row + ((4 + lg) ^ x7) * 8];
    short8 qb0 = *(const short8*)&smem[q1row + (lg ^ x7) * 8];
    short8 qb1 = *(const short8*)&smem[q1row + ((4 + lg) ^ x7) * 8];
    __syncthreads();

    short8 vone;
    #pragma unroll
    for (int i = 0; i < 8; i++) vone[i] = (short)0x3F80;

    int krow = tid >> 3;
    int kunit = (tid & 7) ^ (krow & 7);
    const ushort* kg = qkv + (size_t)(split * 1024 + krow) * 2304 + DMODEL + h * HDIM + kunit * 8;
    const ushort* vgp = vT + (size_t)(h * HDIM + krow) * TSEQ + split * 1024 + kunit * 8;

    gl_lds16(kg, &smem[tid * 8]);
    gl_lds16(vgp, &smem[8192 + tid * 8]);
    kg += 64 * 2304;
    vgp += 64;

    f32x4 o0[4] = {}, o1[4] = {};
    f32x4 s0sum = {}, s1sum = {};
    const int NT = 16;
    int prow0 = (wid * 32 + lr) * 40;
    int prow1 = prow0 + 16 * 40;

    for (int kt = 0; kt < NT; kt++) {
        int cur = kt & 1, nb = cur ^ 1;
        __syncthreads();
        if (kt + 1 < NT) {
            gl_lds16(kg, &smem[nb * 4096 + tid * 8]);
            gl_lds16(vgp, &smem[8192 + nb * 4096 + tid * 8]);
            kg += 64 * 2304;
            vgp += 64;
        }
        const ushort* kb = &smem[cur * 4096];
        const ushort* vb = &smem[8192 + cur * 4096];

        f32x4 st0[4] = {}, st1[4] = {};
        __builtin_amdgcn_s_setprio(1);
        #pragma unroll
        for (int ki = 0; ki < 4; ki++) {
            const ushort* kr = &kb[(ki * 16 + lr) * 64];
            short8 k0 = *(const short8*)&kr[(lg ^ x7) * 8];
            short8 k1 = *(const short8*)&kr[((4 + lg) ^ x7) * 8];
            st0[ki] = __builtin_amdgcn_mfma_f32_16x16x32_bf16(k0, qa0, st0[ki], 0, 0, 0);
            st0[ki] = __builtin_amdgcn_mfma_f32_16x16x32_bf16(k1, qa1, st0[ki], 0, 0, 0);
            st1[ki] = __builtin_amdgcn_mfma_f32_16x16x32_bf16(k0, qb0, st1[ki], 0, 0, 0);
            st1[ki] = __builtin_amdgcn_mfma_f32_16x16x32_bf16(k1, qb1, st1[ki], 0, 0, 0);
        }
        __builtin_amdgcn_s_setprio(0);

        uint2 c0[4], c1[4];
        #pragma unroll
        for (int ki = 0; ki < 4; ki++) {
            #pragma unroll
            for (int r = 0; r < 4; r++) st0[ki][r] = exp2f(st0[ki][r] * C1 - KC);
            asm("v_cvt_pk_bf16_f32 %0, %1, %2" : "=v"(c0[ki].x) : "v"(st0[ki][0]), "v"(st0[ki][1]));
            asm("v_cvt_pk_bf16_f32 %0, %1, %2" : "=v"(c0[ki].y) : "v"(st0[ki][2]), "v"(st0[ki][3]));
        }
        #pragma unroll
        for (int ki = 0; ki < 4; ki++) {
            #pragma unroll
            for (int r = 0; r < 4; r++) st1[ki][r] = exp2f(st1[ki][r] * C1 - KC);
            asm("v_cvt_pk_bf16_f32 %0, %1, %2" : "=v"(c1[ki].x) : "v"(st1[ki][0]), "v"(st1[ki][1]));
            asm("v_cvt_pk_bf16_f32 %0, %1, %2" : "=v"(c1[ki].y) : "v"(st1[ki][2]), "v"(st1[ki][3]));
        }

        *(uint2*)&Ps[prow0 + lg * 4]      = c0[0];
        *(uint2*)&Ps[prow0 + 16 + lg * 4] = c0[1];
        *(uint2*)&Ps[prow1 + lg * 4]      = c1[0];
        *(uint2*)&Ps[prow1 + 16 + lg * 4] = c1[1];
        {
            short8 pa00 = *(const short8*)&Ps[prow0 + lg * 8];
            short8 pa10 = *(const short8*)&Ps[prow1 + lg * 8];
            __builtin_amdgcn_s_setprio(1);
            s0sum = __builtin_amdgcn_mfma_f32_16x16x32_bf16(pa00, vone, s0sum, 0, 0, 0);
            s1sum = __builtin_amdgcn_mfma_f32_16x16x32_bf16(pa10, vone, s1sum, 0, 0, 0);
            #pragma unroll
            for (int ni = 0; ni < 4; ni++) {
                short8 b0 = *(const short8*)&vb[(ni * 16 + lr) * 64 + (lg ^ x7) * 8];
                o0[ni] = __builtin_amdgcn_mfma_f32_16x16x32_bf16(pa00, b0, o0[ni], 0, 0, 0);
                o1[ni] = __builtin_amdgcn_mfma_f32_16x16x32_bf16(pa10, b0, o1[ni], 0, 0, 0);
            }
            __builtin_amdgcn_s_setprio(0);
        }
        *(uint2*)&Ps[prow0 + lg * 4]      = c0[2];
        *(uint2*)&Ps[prow0 + 16 + lg * 4] = c0[3];
        *(uint2*)&Ps[prow1 + lg * 4]      = c1[2];
        *(uint2*)&Ps[prow1 + 16 + lg * 4] = c1[3];
        {
            short8 pa01 = *(const short8*)&Ps[prow0 + lg * 8];
            short8 pa11 = *(const short8*)&Ps[prow1 + lg * 8];
            __builtin_amdgcn_s_setprio(1);
            s0sum = __builtin_amdgcn_mfma_f32_16x16x32_bf16(pa01, vone, s0sum, 0, 0, 0);
            s1sum = __builtin_amdgcn_mfma_f32_16x16x32_bf16(pa11, vone, s1sum, 0, 0, 0);
            #pragma unroll
            for (int ni = 0; ni < 4; ni++) {
                short8 b1 = *(const short8*)&vb[(ni * 16 + lr) * 64 + ((4 + lg) ^ x7) * 8];
                o0[ni] = __builtin_amdgcn_mfma_f32_16x16x32_bf16(pa01, b1, o0[ni], 0, 0, 0);
                o1[ni] = __builtin_amdgcn_mfma_f32_16x16x32_bf16(pa11, b1, o1[ni], 0, 0, 0);
            }
            __builtin_amdgcn_s_setprio(0);
        }
    }

    if (lr == 0) {
        #pragma unroll
        for (int r = 0; r < 4; r++) {
            int q0 = qblk * 256 + wid * 32 + lg * 4 + r;
            ml[((size_t)split * NHEADS + h) * TSEQ + q0]      = s0sum[r];
            ml[((size_t)split * NHEADS + h) * TSEQ + q0 + 16] = s1sum[r];
        }
    }
    #pragma unroll
    for (int ni = 0; ni < 4; ni++)
        #pragma unroll
        for (int r = 0; r < 4; r++) {
            int q0 = qblk * 256 + wid * 32 + lg * 4 + r;
            int dcol = ni * 16 + lr;
            Opart[((size_t)split * TSEQ + q0) * DMODEL + h * HDIM + dcol]      = f2bf(o0[ni][r]);
            Opart[((size_t)split * TSEQ + q0 + 16) * DMODEL + h * HDIM + dcol] = f2bf(o1[ni][r]);
        }
}

// ---------------- combine 4 split partials -> attn bf16 ----------------
__global__ __launch_bounds__(256) void attn_combine_kernel(
    const ushort* __restrict__ Opart, const float* __restrict__ ml,
    ushort* __restrict__ attnb)
{
    int gid = blockIdx.x * 256 + threadIdx.x;
    int q = gid / 192;
    int c = (gid - q * 192) * 4;
    int hh = c >> 6;
    float denom = 0.f;
    float a0 = 0.f, a1 = 0.f, a2 = 0.f, a3 = 0.f;
    #pragma unroll
    for (int s = 0; s < 4; s++) {
        denom += ml[((size_t)s * NHEADS + hh) * TSEQ + q];
        uint2 ov = *(const uint2*)&Opart[((size_t)s * TSEQ + q) * DMODEL + c];
        a0 += asf(ov.x << 16);
        a1 += asf(ov.x & 0xFFFF0000u);
        a2 += asf(ov.y << 16);
        a3 += asf(ov.y & 0xFFFF0000u);
    }
    float rd = 1.f / denom;
    uint2 stv;
    stv.x = (uint)f2bf(a0 * rd) | ((uint)f2bf(a1 * rd) << 16);
    stv.y = (uint)f2bf(a2 * rd) | ((uint)f2bf(a3 * rd) << 16);
    *(uint2*)&attnb[(size_t)q * DMODEL + c] = stv;
}

// ---------------- host launch ----------------
extern "C" void kernel_launch(void* const* d_in, const int* in_sizes, int n_in,
                              void* d_out, int out_size, void* d_ws, size_t ws_size,
                              hipStream_t stream)
{
    const float* x      = (const float*)d_in[0];
    const float* ln1_g  = (const float*)d_in[1];
    const float* ln1_b  = (const float*)d_in[2];
    const float* ln2_g  = (const float*)d_in[3];
    const float* ln2_b  = (const float*)d_in[4];
    const float* qkv_w  = (const float*)d_in[5];
    const float* qkv_b  = (const float*)d_in[6];
    const float* out_w  = (const float*)d_in[7];
    const float* out_b  = (const float*)d_in[8];
    const float* fc1_w  = (const float*)d_in[9];
    const float* fc1_b  = (const float*)d_in[10];
    const float* fc2_w  = (const float*)d_in[11];
    const float* fc2_b  = (const float*)d_in[12];
    (void)in_sizes; (void)n_in; (void)out_size; (void)ws_size;

    char* p = (char*)d_ws;
    ushort* qkvb  = (ushort*)p;                 p += (size_t)TSEQ * DFF * 2;          // also gelu-out
    ushort* hb    = (ushort*)p;                 p += (size_t)TSEQ * DMODEL * 2;
    ushort* attnb = (ushort*)p;                 p += (size_t)TSEQ * DMODEL * 2;
    float*  x2    = (float*)p;                  p += (size_t)TSEQ * DMODEL * 4;
    ushort* qkv_wT = (ushort*)p;                p += (size_t)(3 * DMODEL) * DMODEL * 2;
    ushort* out_wT = (ushort*)p;                p += (size_t)DMODEL * DMODEL * 2;
    ushort* fc1_wT = (ushort*)p;                p += (size_t)DFF * DMODEL * 2;
    ushort* fc2_wT = (ushort*)p;                p += (size_t)DMODEL * DFF * 2;
    ushort* Opart  = (ushort*)p;                p += (size_t)4 * TSEQ * DMODEL * 2;
    float*  mlbuf  = (float*)p;                 p += (size_t)4 * NHEADS * TSEQ * 4;
    ushort* vTb    = (ushort*)p;                p += (size_t)DMODEL * TSEQ * 2;
    ushort* gb = qkvb;

    transpose_all_kernel<<<6912, 256, 0, stream>>>(
        qkv_w, out_w, fc1_w, fc2_w, qkv_wT, out_wT, fc1_wT, fc2_wT);

    ln_half_kernel<<<TSEQ, 256, 0, stream>>>(x, ln1_g, ln1_b, hb);
    // QKV GEMM (128x128 tiles, fused V-transpose epilogue)
    gemm_kernel<3><<<dim3(TSEQ / 128, 3 * DMODEL / 128), 256, 0, stream>>>(
        hb, qkv_wT, qkv_b, nullptr, qkvb, vTb, TSEQ, 3 * DMODEL, DMODEL);
    attn_kernel<<<dim3((TSEQ / 256) * NHEADS * 4), 512, 0, stream>>>(qkvb, vTb, Opart, mlbuf);
    attn_combine_kernel<<<(TSEQ * DMODEL / 4) / 256, 256, 0, stream>>>(Opart, mlbuf, attnb);
    gemm_64_kernel<2><<<dim3(TSEQ / 64, DMODEL / 64), 256, 0, stream>>>(
        attnb, out_wT, out_b, x, x2, TSEQ, DMODEL, DMODEL);
    ln_half_kernel<<<TSEQ, 256, 0, stream>>>(x2, ln2_g, ln2_b, hb);
    gemm_kernel<1><<<dim3(TSEQ / 128, DFF / 128), 256, 0, stream>>>(
        hb, fc1_wT, fc1_b, nullptr, gb, nullptr, TSEQ, DFF, DMODEL);
    gemm_64_kernel<2><<<dim3(TSEQ / 64, DMODEL / 64), 256, 0, stream>>>(
        gb, fc2_wT, fc2_b, x2, (float*)d_out, TSEQ, DMODEL, DFF);
}

// Round 19
// 204.127 us; speedup vs baseline: 1.0935x; 1.0082x over previous
//
#include <hip/hip_runtime.h>
#include <hip/hip_bf16.h>
#include <math.h>

#define TSEQ 4096
#define DMODEL 768
#define DFF 3072
#define NHEADS 12
#define HDIM 64

typedef __attribute__((ext_vector_type(8))) short short8;
typedef __attribute__((ext_vector_type(4))) float f32x4;
typedef unsigned short ushort;
typedef unsigned int uint;

typedef __attribute__((address_space(1))) ushort as1_ushort;
typedef __attribute__((address_space(3))) ushort as3_ushort;

__device__ __forceinline__ void gl_lds16(const ushort* g, const ushort* l) {
    __builtin_amdgcn_global_load_lds((as1_ushort*)(uintptr_t)g,
                                     (as3_ushort*)(uint)(uintptr_t)l, 16, 0, 0);
}

__device__ __forceinline__ ushort f2bf(float f) {
    union { float f; unsigned i; } c; c.f = f;
    unsigned x = c.i;
    unsigned r = x + 0x7FFFu + ((x >> 16) & 1u);
    return (ushort)(r >> 16);
}
__device__ __forceinline__ float asf(uint u) {
    union { unsigned i; float f; } c; c.i = u; return c.f;
}
// tanh-form GELU
__device__ __forceinline__ float gelu_fast(float v) {
    float y = v * (0.7978845608f + 0.03567740814f * v * v);
    float u = exp2f(y * -2.8853900817779268f);
    float r;
    asm("v_rcp_f32 %0, %1" : "=v"(r) : "v"(1.f + u));
    return v * r;
}

// ---------------- LayerNorm * 0.5 -> bf16 ----------------
__global__ __launch_bounds__(256) void ln_half_kernel(
    const float* __restrict__ x, const float* __restrict__ g,
    const float* __restrict__ b, ushort* __restrict__ out)
{
    int row = blockIdx.x;
    const float* xr = x + (size_t)row * DMODEL;
    float v[3];
    float s = 0.f, s2 = 0.f;
    #pragma unroll
    for (int i = 0; i < 3; i++) {
        v[i] = xr[threadIdx.x + 256 * i];
        s += v[i]; s2 += v[i] * v[i];
    }
    #pragma unroll
    for (int m = 1; m < 64; m <<= 1) { s += __shfl_xor(s, m, 64); s2 += __shfl_xor(s2, m, 64); }
    __shared__ float ss[4], ss2[4];
    int wid = threadIdx.x >> 6;
    if ((threadIdx.x & 63) == 0) { ss[wid] = s; ss2[wid] = s2; }
    __syncthreads();
    s = ss[0] + ss[1] + ss[2] + ss[3];
    s2 = ss2[0] + ss2[1] + ss2[2] + ss2[3];
    float mu = s * (1.f / DMODEL);
    float var = s2 * (1.f / DMODEL) - mu * mu;
    float rs = rsqrtf(var + 1e-5f);
    #pragma unroll
    for (int i = 0; i < 3; i++) {
        int c = threadIdx.x + 256 * i;
        float h = (v[i] - mu) * rs * g[c] + b[c];
        out[(size_t)row * DMODEL + c] = f2bf(h * 0.5f);
    }
}

// ---------------- merged weight transpose+cast: all 4 weights in one launch ----------------
__global__ __launch_bounds__(256) void transpose_all_kernel(
    const float* __restrict__ qkv_w, const float* __restrict__ out_w,
    const float* __restrict__ fc1_w, const float* __restrict__ fc2_w,
    ushort* __restrict__ qkv_wT, ushort* __restrict__ out_wT,
    ushort* __restrict__ fc1_wT, ushort* __restrict__ fc2_wT)
{
    int bid = blockIdx.x;
    const float* in; ushort* out; int K, N, tile_id;
    if (bid < 1728)      { in = qkv_w; out = qkv_wT; K = 768;  N = 2304; tile_id = bid; }
    else if (bid < 2304) { in = out_w; out = out_wT; K = 768;  N = 768;  tile_id = bid - 1728; }
    else if (bid < 4608) { in = fc1_w; out = fc1_wT; K = 768;  N = 3072; tile_id = bid - 2304; }
    else                 { in = fc2_w; out = fc2_wT; K = 3072; N = 768;  tile_id = bid - 4608; }
    int nx = K >> 5;
    int k0 = (tile_id % nx) * 32, n0 = (tile_id / nx) * 32;

    __shared__ float tile[32][33];
    int c = threadIdx.x & 31, r0 = threadIdx.x >> 5;
    #pragma unroll
    for (int i = 0; i < 4; i++) {
        int r = r0 + i * 8;
        tile[r][c] = in[(size_t)(k0 + r) * N + n0 + c];
    }
    __syncthreads();
    #pragma unroll
    for (int i = 0; i < 4; i++) {
        int r = r0 + i * 8;
        out[(size_t)(n0 + r) * K + k0 + c] = f2bf(tile[c][r]);
    }
}

// ---------------- GEMM BN=128 (EPI 0: bias->bf16; 1: bias+GELU->bf16; 2: bias+res->f32;
//   3: QKV fused — Q cols (bn<768) pre-scaled by C1=0.125*log2e; V cols (bn>=1536)
//      written TRANSPOSED to vTout) --------
template<int EPI>
__global__ __launch_bounds__(256) void gemm_kernel(
    const ushort* __restrict__ A, const ushort* __restrict__ Bt,
    const float* __restrict__ bias, const float* __restrict__ res,
    void* __restrict__ out, ushort* __restrict__ vTout, int M, int N, int K)
{
    __shared__ ushort As[2][128 * 32];
    __shared__ ushort Bs[2][128 * 32];
    int bm = blockIdx.x * 128, bn = blockIdx.y * 128;
    int tid = threadIdx.x;
    int wid = tid >> 6, lane = tid & 63;
    int wm = (wid >> 1) * 64, wn = (wid & 1) * 64;
    int lg = lane >> 4, lr = lane & 15;
    int srow = lane >> 2, scol = (lane & 3) * 8;
    f32x4 acc[4][4] = {};

    const ushort* ga0 = A  + (size_t)(bm + wid * 16 + srow) * K + scol;
    const ushort* ga1 = A  + (size_t)(bm + 64 + wid * 16 + srow) * K + scol;
    const ushort* gb0 = Bt + (size_t)(bn + wid * 16 + srow) * K + scol;
    const ushort* gb1 = Bt + (size_t)(bn + 64 + wid * 16 + srow) * K + scol;

    gl_lds16(ga0, &As[0][wid * 512]);
    gl_lds16(ga1, &As[0][2048 + wid * 512]);
    gl_lds16(gb0, &Bs[0][wid * 512]);
    gl_lds16(gb1, &Bs[0][2048 + wid * 512]);

    int nt = K >> 5;
    for (int t = 0; t < nt; t++) {
        int cur = t & 1;
        __syncthreads();
        if (t + 1 < nt) {
            int k0 = (t + 1) << 5;
            int nb = cur ^ 1;
            gl_lds16(ga0 + k0, &As[nb][wid * 512]);
            gl_lds16(ga1 + k0, &As[nb][2048 + wid * 512]);
            gl_lds16(gb0 + k0, &Bs[nb][wid * 512]);
            gl_lds16(gb1 + k0, &Bs[nb][2048 + wid * 512]);
        }
        short8 a[4], b[4];
        #pragma unroll
        for (int mi = 0; mi < 4; mi++) a[mi] = *(const short8*)&As[cur][(wm + mi * 16 + lr) * 32 + lg * 8];
        #pragma unroll
        for (int ni = 0; ni < 4; ni++) b[ni] = *(const short8*)&Bs[cur][(wn + ni * 16 + lr) * 32 + lg * 8];
        #pragma unroll
        for (int mi = 0; mi < 4; mi++)
            #pragma unroll
            for (int ni = 0; ni < 4; ni++)
                acc[mi][ni] = __builtin_amdgcn_mfma_f32_16x16x32_bf16(a[mi], b[ni], acc[mi][ni], 0, 0, 0);
    }

    const float C1 = 0.18033688011112042f;
    #pragma unroll
    for (int mi = 0; mi < 4; mi++) {
        #pragma unroll
        for (int ni = 0; ni < 4; ni++) {
            int col = bn + wn + ni * 16 + lr;
            float bv = bias[col];
            if (EPI == 3 && bn >= 1536) {
                // V columns -> vT[col-1536][row], 4 consecutive rows packed (8B store)
                int row0 = bm + wm + mi * 16 + lg * 4;
                uint2 pk;
                pk.x = (uint)f2bf(acc[mi][ni][0] + bv) | ((uint)f2bf(acc[mi][ni][1] + bv) << 16);
                pk.y = (uint)f2bf(acc[mi][ni][2] + bv) | ((uint)f2bf(acc[mi][ni][3] + bv) << 16);
                *(uint2*)&vTout[(size_t)(col - 1536) * TSEQ + row0] = pk;
            } else {
                #pragma unroll
                for (int r = 0; r < 4; r++) {
                    int row = bm + wm + mi * 16 + lg * 4 + r;
                    float v = acc[mi][ni][r] + bv;
                    size_t idx = (size_t)row * N + col;
                    if (EPI == 1) {
                        ((ushort*)out)[idx] = f2bf(gelu_fast(v));
                    } else if (EPI == 2) {
                        ((float*)out)[idx] = v + res[idx];
                    } else if (EPI == 3) {
                        // Q cols pre-scaled by C1 (bn<768); K cols unscaled
                        ((ushort*)out)[idx] = f2bf(bn < 768 ? v * C1 : v);
                    } else {
                        ((ushort*)out)[idx] = f2bf(v);
                    }
                }
            }
        }
    }
}

// ---------------- GEMM 64x64 (skinny-N: out-proj, FC2) ----------------
template<int EPI>
__global__ __launch_bounds__(256) void gemm_64_kernel(
    const ushort* __restrict__ A, const ushort* __restrict__ Bt,
    const float* __restrict__ bias, const float* __restrict__ res,
    void* __restrict__ out, int M, int N, int K)
{
    __shared__ ushort As[2][64 * 32];
    __shared__ ushort Bs[2][64 * 32];
    int bm = blockIdx.x * 64, bn = blockIdx.y * 64;
    int tid = threadIdx.x;
    int wid = tid >> 6, lane = tid & 63;
    int wm = (wid >> 1) * 32, wn = (wid & 1) * 32;
    int lg = lane >> 4, lr = lane & 15;
    int srow = tid >> 2;
    int sunit = (tid & 3) ^ (srow & 3);
    f32x4 acc[2][2] = {};

    const ushort* ga = A  + (size_t)(bm + srow) * K + sunit * 8;
    const ushort* gb = Bt + (size_t)(bn + srow) * K + sunit * 8;

    gl_lds16(ga, &As[0][tid * 8]);
    gl_lds16(gb, &Bs[0][tid * 8]);

    int nt = K >> 5;
    for (int t = 0; t < nt; t++) {
        int cur = t & 1;
        __syncthreads();
        if (t + 1 < nt) {
            int k0 = (t + 1) << 5;
            int nb = cur ^ 1;
            gl_lds16(ga + k0, &As[nb][tid * 8]);
            gl_lds16(gb + k0, &Bs[nb][tid * 8]);
        }
        short8 a[2], b[2];
        #pragma unroll
        for (int mi = 0; mi < 2; mi++) {
            int row = wm + mi * 16 + lr;
            a[mi] = *(const short8*)&As[cur][row * 32 + ((lg ^ (row & 3)) * 8)];
        }
        #pragma unroll
        for (int ni = 0; ni < 2; ni++) {
            int row = wn + ni * 16 + lr;
            b[ni] = *(const short8*)&Bs[cur][row * 32 + ((lg ^ (row & 3)) * 8)];
        }
        #pragma unroll
        for (int mi = 0; mi < 2; mi++)
            #pragma unroll
            for (int ni = 0; ni < 2; ni++)
                acc[mi][ni] = __builtin_amdgcn_mfma_f32_16x16x32_bf16(a[mi], b[ni], acc[mi][ni], 0, 0, 0);
    }

    #pragma unroll
    for (int mi = 0; mi < 2; mi++) {
        #pragma unroll
        for (int ni = 0; ni < 2; ni++) {
            int col = bn + wn + ni * 16 + lr;
            float bv = bias[col];
            #pragma unroll
            for (int r = 0; r < 4; r++) {
                int row = bm + wm + mi * 16 + lg * 4 + r;
                float v = acc[mi][ni][r] + bv;
                size_t idx = (size_t)row * N + col;
                if (EPI == 0) {
                    ((ushort*)out)[idx] = f2bf(v);
                } else if (EPI == 1) {
                    ((ushort*)out)[idx] = f2bf(gelu_fast(v));
                } else {
                    ((float*)out)[idx] = v + res[idx];
                }
            }
        }
    }
}

// ---------------- flash attention (split-K x4, QBLK=256, 52KB LDS, XCD-local KV) ----------------
// Q pre-scaled by C1 in the QKV epilogue -> per-element softmax is a bare v_exp_f32
// (the -KC offset cancels in O/lsum and is dropped entirely).
__global__ __launch_bounds__(512) void attn_kernel(
    const ushort* __restrict__ qkv, const ushort* __restrict__ vT,
    ushort* __restrict__ Opart, float* __restrict__ ml)
{
    int combo = blockIdx.x % 48;
    int qblk  = blockIdx.x / 48;
    int h     = combo >> 2;
    int split = combo & 3;
    __shared__ ushort smem[16384 + 256 * 40];    // K/V dbuf (32KB) + P scratch (20KB)
    ushort* Ps = smem + 16384;
    int tid = threadIdx.x, wid = tid >> 6, lane = tid & 63;
    int lg = lane >> 4, lr = lane & 15;
    int x7 = lr & 7;

    { // stage Q: dest-XOR swizzled LDS, linear global source
        int row = tid >> 1;
        int u0 = (tid & 1) * 4;
        int r7 = row & 7;
        const ushort* src = qkv + (size_t)(qblk * 256 + row) * 2304 + h * HDIM;
        #pragma unroll
        for (int i = 0; i < 4; i++) {
            int u = u0 + i;
            *(short8*)&smem[row * 64 + ((u ^ r7) * 8)] = *(const short8*)(src + (size_t)(u * 8));
        }
    }
    int q0row = (wid * 32 + lr) * 64;
    int q1row = q0row + 16 * 64;
    short8 qa0 = *(const short8*)&smem[q0row + (lg ^ x7) * 8];
    short8 qa1 = *(const short8*)&smem[q0row + ((4 + lg) ^ x7) * 8];
    short8 qb0 = *(const short8*)&smem[q1row + (lg ^ x7) * 8];
    short8 qb1 = *(const short8*)&smem[q1row + ((4 + lg) ^ x7) * 8];
    __syncthreads();

    short8 vone;
    #pragma unroll
    for (int i = 0; i < 8; i++) vone[i] = (short)0x3F80;

    int krow = tid >> 3;
    int kunit = (tid & 7) ^ (krow & 7);
    const ushort* kg = qkv + (size_t)(split * 1024 + krow) * 2304 + DMODEL + h * HDIM + kunit * 8;
    const ushort* vgp = vT + (size_t)(h * HDIM + krow) * TSEQ + split * 1024 + kunit * 8;

    gl_lds16(kg, &smem[tid * 8]);
    gl_lds16(vgp, &smem[8192 + tid * 8]);
    kg += 64 * 2304;
    vgp += 64;

    f32x4 o0[4] = {}, o1[4] = {};
    f32x4 s0sum = {}, s1sum = {};
    const int NT = 16;
    int prow0 = (wid * 32 + lr) * 40;
    int prow1 = prow0 + 16 * 40;

    for (int kt = 0; kt < NT; kt++) {
        int cur = kt & 1, nb = cur ^ 1;
        __syncthreads();
        if (kt + 1 < NT) {
            gl_lds16(kg, &smem[nb * 4096 + tid * 8]);
            gl_lds16(vgp, &smem[8192 + nb * 4096 + tid * 8]);
            kg += 64 * 2304;
            vgp += 64;
        }
        const ushort* kb = &smem[cur * 4096];
        const ushort* vb = &smem[8192 + cur * 4096];

        f32x4 st0[4] = {}, st1[4] = {};
        __builtin_amdgcn_s_setprio(1);
        #pragma unroll
        for (int ki = 0; ki < 4; ki++) {
            const ushort* kr = &kb[(ki * 16 + lr) * 64];
            short8 k0 = *(const short8*)&kr[(lg ^ x7) * 8];
            short8 k1 = *(const short8*)&kr[((4 + lg) ^ x7) * 8];
            st0[ki] = __builtin_amdgcn_mfma_f32_16x16x32_bf16(k0, qa0, st0[ki], 0, 0, 0);
            st0[ki] = __builtin_amdgcn_mfma_f32_16x16x32_bf16(k1, qa1, st0[ki], 0, 0, 0);
            st1[ki] = __builtin_amdgcn_mfma_f32_16x16x32_bf16(k0, qb0, st1[ki], 0, 0, 0);
            st1[ki] = __builtin_amdgcn_mfma_f32_16x16x32_bf16(k1, qb1, st1[ki], 0, 0, 0);
        }
        __builtin_amdgcn_s_setprio(0);

        // bare exp2 (Q pre-scaled by C1; constant offset cancels in O/lsum)
        uint2 c0[4], c1[4];
        #pragma unroll
        for (int ki = 0; ki < 4; ki++) {
            #pragma unroll
            for (int r = 0; r < 4; r++) st0[ki][r] = exp2f(st0[ki][r]);
            asm("v_cvt_pk_bf16_f32 %0, %1, %2" : "=v"(c0[ki].x) : "v"(st0[ki][0]), "v"(st0[ki][1]));
            asm("v_cvt_pk_bf16_f32 %0, %1, %2" : "=v"(c0[ki].y) : "v"(st0[ki][2]), "v"(st0[ki][3]));
        }
        #pragma unroll
        for (int ki = 0; ki < 4; ki++) {
            #pragma unroll
            for (int r = 0; r < 4; r++) st1[ki][r] = exp2f(st1[ki][r]);
            asm("v_cvt_pk_bf16_f32 %0, %1, %2" : "=v"(c1[ki].x) : "v"(st1[ki][0]), "v"(st1[ki][1]));
            asm("v_cvt_pk_bf16_f32 %0, %1, %2" : "=v"(c1[ki].y) : "v"(st1[ki][2]), "v"(st1[ki][3]));
        }

        *(uint2*)&Ps[prow0 + lg * 4]      = c0[0];
        *(uint2*)&Ps[prow0 + 16 + lg * 4] = c0[1];
        *(uint2*)&Ps[prow1 + lg * 4]      = c1[0];
        *(uint2*)&Ps[prow1 + 16 + lg * 4] = c1[1];
        {
            short8 pa00 = *(const short8*)&Ps[prow0 + lg * 8];
            short8 pa10 = *(const short8*)&Ps[prow1 + lg * 8];
            __builtin_amdgcn_s_setprio(1);
            s0sum = __builtin_amdgcn_mfma_f32_16x16x32_bf16(pa00, vone, s0sum, 0, 0, 0);
            s1sum = __builtin_amdgcn_mfma_f32_16x16x32_bf16(pa10, vone, s1sum, 0, 0, 0);
            #pragma unroll
            for (int ni = 0; ni < 4; ni++) {
                short8 b0 = *(const short8*)&vb[(ni * 16 + lr) * 64 + (lg ^ x7) * 8];
                o0[ni] = __builtin_amdgcn_mfma_f32_16x16x32_bf16(pa00, b0, o0[ni], 0, 0, 0);
                o1[ni] = __builtin_amdgcn_mfma_f32_16x16x32_bf16(pa10, b0, o1[ni], 0, 0, 0);
            }
            __builtin_amdgcn_s_setprio(0);
        }
        *(uint2*)&Ps[prow0 + lg * 4]      = c0[2];
        *(uint2*)&Ps[prow0 + 16 + lg * 4] = c0[3];
        *(uint2*)&Ps[prow1 + lg * 4]      = c1[2];
        *(uint2*)&Ps[prow1 + 16 + lg * 4] = c1[3];
        {
            short8 pa01 = *(const short8*)&Ps[prow0 + lg * 8];
            short8 pa11 = *(const short8*)&Ps[prow1 + lg * 8];
            __builtin_amdgcn_s_setprio(1);
            s0sum = __builtin_amdgcn_mfma_f32_16x16x32_bf16(pa01, vone, s0sum, 0, 0, 0);
            s1sum = __builtin_amdgcn_mfma_f32_16x16x32_bf16(pa11, vone, s1sum, 0, 0, 0);
            #pragma unroll
            for (int ni = 0; ni < 4; ni++) {
                short8 b1 = *(const short8*)&vb[(ni * 16 + lr) * 64 + ((4 + lg) ^ x7) * 8];
                o0[ni] = __builtin_amdgcn_mfma_f32_16x16x32_bf16(pa01, b1, o0[ni], 0, 0, 0);
                o1[ni] = __builtin_amdgcn_mfma_f32_16x16x32_bf16(pa11, b1, o1[ni], 0, 0, 0);
            }
            __builtin_amdgcn_s_setprio(0);
        }
    }

    if (lr == 0) {
        #pragma unroll
        for (int r = 0; r < 4; r++) {
            int q0 = qblk * 256 + wid * 32 + lg * 4 + r;
            ml[((size_t)split * NHEADS + h) * TSEQ + q0]      = s0sum[r];
            ml[((size_t)split * NHEADS + h) * TSEQ + q0 + 16] = s1sum[r];
        }
    }
    #pragma unroll
    for (int ni = 0; ni < 4; ni++)
        #pragma unroll
        for (int r = 0; r < 4; r++) {
            int q0 = qblk * 256 + wid * 32 + lg * 4 + r;
            int dcol = ni * 16 + lr;
            Opart[((size_t)split * TSEQ + q0) * DMODEL + h * HDIM + dcol]      = f2bf(o0[ni][r]);
            Opart[((size_t)split * TSEQ + q0 + 16) * DMODEL + h * HDIM + dcol] = f2bf(o1[ni][r]);
        }
}

// ---------------- combine 4 split partials -> attn bf16 ----------------
__global__ __launch_bounds__(256) void attn_combine_kernel(
    const ushort* __restrict__ Opart, const float* __restrict__ ml,
    ushort* __restrict__ attnb)
{
    int gid = blockIdx.x * 256 + threadIdx.x;
    int q = gid / 192;
    int c = (gid - q * 192) * 4;
    int hh = c >> 6;
    float denom = 0.f;
    float a0 = 0.f, a1 = 0.f, a2 = 0.f, a3 = 0.f;
    #pragma unroll
    for (int s = 0; s < 4; s++) {
        denom += ml[((size_t)s * NHEADS + hh) * TSEQ + q];
        uint2 ov = *(const uint2*)&Opart[((size_t)s * TSEQ + q) * DMODEL + c];
        a0 += asf(ov.x << 16);
        a1 += asf(ov.x & 0xFFFF0000u);
        a2 += asf(ov.y << 16);
        a3 += asf(ov.y & 0xFFFF0000u);
    }
    float rd = 1.f / denom;
    uint2 stv;
    stv.x = (uint)f2bf(a0 * rd) | ((uint)f2bf(a1 * rd) << 16);
    stv.y = (uint)f2bf(a2 * rd) | ((uint)f2bf(a3 * rd) << 16);
    *(uint2*)&attnb[(size_t)q * DMODEL + c] = stv;
}

// ---------------- host launch ----------------
extern "C" void kernel_launch(void* const* d_in, const int* in_sizes, int n_in,
                              void* d_out, int out_size, void* d_ws, size_t ws_size,
                              hipStream_t stream)
{
    const float* x      = (const float*)d_in[0];
    const float* ln1_g  = (const float*)d_in[1];
    const float* ln1_b  = (const float*)d_in[2];
    const float* ln2_g  = (const float*)d_in[3];
    const float* ln2_b  = (const float*)d_in[4];
    const float* qkv_w  = (const float*)d_in[5];
    const float* qkv_b  = (const float*)d_in[6];
    const float* out_w  = (const float*)d_in[7];
    const float* out_b  = (const float*)d_in[8];
    const float* fc1_w  = (const float*)d_in[9];
    const float* fc1_b  = (const float*)d_in[10];
    const float* fc2_w  = (const float*)d_in[11];
    const float* fc2_b  = (const float*)d_in[12];
    (void)in_sizes; (void)n_in; (void)out_size; (void)ws_size;

    char* p = (char*)d_ws;
    ushort* qkvb  = (ushort*)p;                 p += (size_t)TSEQ * DFF * 2;          // also gelu-out
    ushort* hb    = (ushort*)p;                 p += (size_t)TSEQ * DMODEL * 2;
    ushort* attnb = (ushort*)p;                 p += (size_t)TSEQ * DMODEL * 2;
    float*  x2    = (float*)p;                  p += (size_t)TSEQ * DMODEL * 4;
    ushort* qkv_wT = (ushort*)p;                p += (size_t)(3 * DMODEL) * DMODEL * 2;
    ushort* out_wT = (ushort*)p;                p += (size_t)DMODEL * DMODEL * 2;
    ushort* fc1_wT = (ushort*)p;                p += (size_t)DFF * DMODEL * 2;
    ushort* fc2_wT = (ushort*)p;                p += (size_t)DMODEL * DFF * 2;
    ushort* Opart  = (ushort*)p;                p += (size_t)4 * TSEQ * DMODEL * 2;
    float*  mlbuf  = (float*)p;                 p += (size_t)4 * NHEADS * TSEQ * 4;
    ushort* vTb    = (ushort*)p;                p += (size_t)DMODEL * TSEQ * 2;
    ushort* gb = qkvb;

    transpose_all_kernel<<<6912, 256, 0, stream>>>(
        qkv_w, out_w, fc1_w, fc2_w, qkv_wT, out_wT, fc1_wT, fc2_wT);

    ln_half_kernel<<<TSEQ, 256, 0, stream>>>(x, ln1_g, ln1_b, hb);
    gemm_kernel<3><<<dim3(TSEQ / 128, 3 * DMODEL / 128), 256, 0, stream>>>(
        hb, qkv_wT, qkv_b, nullptr, qkvb, vTb, TSEQ, 3 * DMODEL, DMODEL);
    attn_kernel<<<dim3((TSEQ / 256) * NHEADS * 4), 512, 0, stream>>>(qkvb, vTb, Opart, mlbuf);
    attn_combine_kernel<<<(TSEQ * DMODEL / 4) / 256, 256, 0, stream>>>(Opart, mlbuf, attnb);
    gemm_64_kernel<2><<<dim3(TSEQ / 64, DMODEL / 64), 256, 0, stream>>>(
        attnb, out_wT, out_b, x, x2, TSEQ, DMODEL, DMODEL);
    ln_half_kernel<<<TSEQ, 256, 0, stream>>>(x2, ln2_g, ln2_b, hb);
    gemm_kernel<1><<<dim3(TSEQ / 128, DFF / 128), 256, 0, stream>>>(
        hb, fc1_wT, fc1_b, nullptr, gb, nullptr, TSEQ, DFF, DMODEL);
    gemm_64_kernel<2><<<dim3(TSEQ / 64, DMODEL / 64), 256, 0, stream>>>(
        gb, fc2_wT, fc2_b, x2, (float*)d_out, TSEQ, DMODEL, DFF);
}

// Round 20
// 200.753 us; speedup vs baseline: 1.1119x; 1.0168x over previous
//
#include <hip/hip_runtime.h>
#include <hip/hip_bf16.h>
#include <math.h>

#define TSEQ 4096
#define DMODEL 768
#define DFF 3072
#define NHEADS 12
#define HDIM 64

typedef __attribute__((ext_vector_type(8))) short short8;
typedef __attribute__((ext_vector_type(4))) float f32x4;
typedef unsigned short ushort;
typedef unsigned int uint;

typedef __attribute__((address_space(1))) ushort as1_ushort;
typedef __attribute__((address_space(3))) ushort as3_ushort;

__device__ __forceinline__ void gl_lds16(const ushort* g, const ushort* l) {
    __builtin_amdgcn_global_load_lds((as1_ushort*)(uintptr_t)g,
                                     (as3_ushort*)(uint)(uintptr_t)l, 16, 0, 0);
}

__device__ __forceinline__ ushort f2bf(float f) {
    union { float f; unsigned i; } c; c.f = f;
    unsigned x = c.i;
    unsigned r = x + 0x7FFFu + ((x >> 16) & 1u);
    return (ushort)(r >> 16);
}
__device__ __forceinline__ float asf(uint u) {
    union { unsigned i; float f; } c; c.i = u; return c.f;
}
// tanh-form GELU
__device__ __forceinline__ float gelu_fast(float v) {
    float y = v * (0.7978845608f + 0.03567740814f * v * v);
    float u = exp2f(y * -2.8853900817779268f);
    float r;
    asm("v_rcp_f32 %0, %1" : "=v"(r) : "v"(1.f + u));
    return v * r;
}

// ---------------- LayerNorm * 0.5 -> bf16 (ln2 only; ln1 fused into prep) ----------------
__global__ __launch_bounds__(256) void ln_half_kernel(
    const float* __restrict__ x, const float* __restrict__ g,
    const float* __restrict__ b, ushort* __restrict__ out)
{
    int row = blockIdx.x;
    const float* xr = x + (size_t)row * DMODEL;
    float v[3];
    float s = 0.f, s2 = 0.f;
    #pragma unroll
    for (int i = 0; i < 3; i++) {
        v[i] = xr[threadIdx.x + 256 * i];
        s += v[i]; s2 += v[i] * v[i];
    }
    #pragma unroll
    for (int m = 1; m < 64; m <<= 1) { s += __shfl_xor(s, m, 64); s2 += __shfl_xor(s2, m, 64); }
    __shared__ float ss[4], ss2[4];
    int wid = threadIdx.x >> 6;
    if ((threadIdx.x & 63) == 0) { ss[wid] = s; ss2[wid] = s2; }
    __syncthreads();
    s = ss[0] + ss[1] + ss[2] + ss[3];
    s2 = ss2[0] + ss2[1] + ss2[2] + ss2[3];
    float mu = s * (1.f / DMODEL);
    float var = s2 * (1.f / DMODEL) - mu * mu;
    float rs = rsqrtf(var + 1e-5f);
    #pragma unroll
    for (int i = 0; i < 3; i++) {
        int c = threadIdx.x + 256 * i;
        float h = (v[i] - mu) * rs * g[c] + b[c];
        out[(size_t)row * DMODEL + c] = f2bf(h * 0.5f);
    }
}

// ---------------- prep: all 4 weight transposes + LN1, one launch ----------------
// blocks [0,1728) qkv_w ; [1728,2304) out_w ; [2304,4608) fc1_w ; [4608,6912) fc2_w ;
// [6912,11008) LN1*0.5 rows
__global__ __launch_bounds__(256) void prep_kernel(
    const float* __restrict__ qkv_w, const float* __restrict__ out_w,
    const float* __restrict__ fc1_w, const float* __restrict__ fc2_w,
    const float* __restrict__ x, const float* __restrict__ ln1_g,
    const float* __restrict__ ln1_b,
    ushort* __restrict__ qkv_wT, ushort* __restrict__ out_wT,
    ushort* __restrict__ fc1_wT, ushort* __restrict__ fc2_wT,
    ushort* __restrict__ hb)
{
    __shared__ float tile[32][33];
    int bid = blockIdx.x;
    if (bid >= 6912) {
        int row = bid - 6912;
        const float* xr = x + (size_t)row * DMODEL;
        float v[3];
        float s = 0.f, s2 = 0.f;
        #pragma unroll
        for (int i = 0; i < 3; i++) {
            v[i] = xr[threadIdx.x + 256 * i];
            s += v[i]; s2 += v[i] * v[i];
        }
        #pragma unroll
        for (int m = 1; m < 64; m <<= 1) { s += __shfl_xor(s, m, 64); s2 += __shfl_xor(s2, m, 64); }
        float* ss = (float*)tile;
        int wid = threadIdx.x >> 6;
        if ((threadIdx.x & 63) == 0) { ss[wid] = s; ss[4 + wid] = s2; }
        __syncthreads();
        s = ss[0] + ss[1] + ss[2] + ss[3];
        s2 = ss[4] + ss[5] + ss[6] + ss[7];
        float mu = s * (1.f / DMODEL);
        float var = s2 * (1.f / DMODEL) - mu * mu;
        float rs = rsqrtf(var + 1e-5f);
        #pragma unroll
        for (int i = 0; i < 3; i++) {
            int c = threadIdx.x + 256 * i;
            float h = (v[i] - mu) * rs * ln1_g[c] + ln1_b[c];
            hb[(size_t)row * DMODEL + c] = f2bf(h * 0.5f);
        }
        return;
    }
    const float* in; ushort* out; int K, N, tile_id;
    if (bid < 1728)      { in = qkv_w; out = qkv_wT; K = 768;  N = 2304; tile_id = bid; }
    else if (bid < 2304) { in = out_w; out = out_wT; K = 768;  N = 768;  tile_id = bid - 1728; }
    else if (bid < 4608) { in = fc1_w; out = fc1_wT; K = 768;  N = 3072; tile_id = bid - 2304; }
    else                 { in = fc2_w; out = fc2_wT; K = 3072; N = 768;  tile_id = bid - 4608; }
    int nx = K >> 5;
    int k0 = (tile_id % nx) * 32, n0 = (tile_id / nx) * 32;

    int c = threadIdx.x & 31, r0 = threadIdx.x >> 5;
    #pragma unroll
    for (int i = 0; i < 4; i++) {
        int r = r0 + i * 8;
        tile[r][c] = in[(size_t)(k0 + r) * N + n0 + c];
    }
    __syncthreads();
    #pragma unroll
    for (int i = 0; i < 4; i++) {
        int r = r0 + i * 8;
        out[(size_t)(n0 + r) * K + k0 + c] = f2bf(tile[c][r]);
    }
}

// ---------------- GEMM BN=128 (EPI 0: bias->bf16; 1: bias+GELU->bf16; 2: bias+res->f32;
//   3: QKV fused — Q cols (bn<768) pre-scaled by C1=0.125*log2e; V cols (bn>=1536)
//      written TRANSPOSED to vTout) --------
template<int EPI>
__global__ __launch_bounds__(256) void gemm_kernel(
    const ushort* __restrict__ A, const ushort* __restrict__ Bt,
    const float* __restrict__ bias, const float* __restrict__ res,
    void* __restrict__ out, ushort* __restrict__ vTout, int M, int N, int K)
{
    __shared__ ushort As[2][128 * 32];
    __shared__ ushort Bs[2][128 * 32];
    int bm = blockIdx.x * 128, bn = blockIdx.y * 128;
    int tid = threadIdx.x;
    int wid = tid >> 6, lane = tid & 63;
    int wm = (wid >> 1) * 64, wn = (wid & 1) * 64;
    int lg = lane >> 4, lr = lane & 15;
    int srow = lane >> 2, scol = (lane & 3) * 8;
    f32x4 acc[4][4] = {};

    const ushort* ga0 = A  + (size_t)(bm + wid * 16 + srow) * K + scol;
    const ushort* ga1 = A  + (size_t)(bm + 64 + wid * 16 + srow) * K + scol;
    const ushort* gb0 = Bt + (size_t)(bn + wid * 16 + srow) * K + scol;
    const ushort* gb1 = Bt + (size_t)(bn + 64 + wid * 16 + srow) * K + scol;

    gl_lds16(ga0, &As[0][wid * 512]);
    gl_lds16(ga1, &As[0][2048 + wid * 512]);
    gl_lds16(gb0, &Bs[0][wid * 512]);
    gl_lds16(gb1, &Bs[0][2048 + wid * 512]);

    int nt = K >> 5;
    for (int t = 0; t < nt; t++) {
        int cur = t & 1;
        __syncthreads();
        if (t + 1 < nt) {
            int k0 = (t + 1) << 5;
            int nb = cur ^ 1;
            gl_lds16(ga0 + k0, &As[nb][wid * 512]);
            gl_lds16(ga1 + k0, &As[nb][2048 + wid * 512]);
            gl_lds16(gb0 + k0, &Bs[nb][wid * 512]);
            gl_lds16(gb1 + k0, &Bs[nb][2048 + wid * 512]);
        }
        short8 a[4], b[4];
        #pragma unroll
        for (int mi = 0; mi < 4; mi++) a[mi] = *(const short8*)&As[cur][(wm + mi * 16 + lr) * 32 + lg * 8];
        #pragma unroll
        for (int ni = 0; ni < 4; ni++) b[ni] = *(const short8*)&Bs[cur][(wn + ni * 16 + lr) * 32 + lg * 8];
        #pragma unroll
        for (int mi = 0; mi < 4; mi++)
            #pragma unroll
            for (int ni = 0; ni < 4; ni++)
                acc[mi][ni] = __builtin_amdgcn_mfma_f32_16x16x32_bf16(a[mi], b[ni], acc[mi][ni], 0, 0, 0);
    }

    const float C1 = 0.18033688011112042f;
    #pragma unroll
    for (int mi = 0; mi < 4; mi++) {
        #pragma unroll
        for (int ni = 0; ni < 4; ni++) {
            int col = bn + wn + ni * 16 + lr;
            float bv = bias[col];
            if (EPI == 3 && bn >= 1536) {
                int row0 = bm + wm + mi * 16 + lg * 4;
                uint2 pk;
                pk.x = (uint)f2bf(acc[mi][ni][0] + bv) | ((uint)f2bf(acc[mi][ni][1] + bv) << 16);
                pk.y = (uint)f2bf(acc[mi][ni][2] + bv) | ((uint)f2bf(acc[mi][ni][3] + bv) << 16);
                *(uint2*)&vTout[(size_t)(col - 1536) * TSEQ + row0] = pk;
            } else {
                #pragma unroll
                for (int r = 0; r < 4; r++) {
                    int row = bm + wm + mi * 16 + lg * 4 + r;
                    float v = acc[mi][ni][r] + bv;
                    size_t idx = (size_t)row * N + col;
                    if (EPI == 1) {
                        ((ushort*)out)[idx] = f2bf(gelu_fast(v));
                    } else if (EPI == 2) {
                        ((float*)out)[idx] = v + res[idx];
                    } else if (EPI == 3) {
                        ((ushort*)out)[idx] = f2bf(bn < 768 ? v * C1 : v);
                    } else {
                        ((ushort*)out)[idx] = f2bf(v);
                    }
                }
            }
        }
    }
}

// ---------------- GEMM 64x64 (skinny-N: out-proj, FC2) ----------------
template<int EPI>
__global__ __launch_bounds__(256) void gemm_64_kernel(
    const ushort* __restrict__ A, const ushort* __restrict__ Bt,
    const float* __restrict__ bias, const float* __restrict__ res,
    void* __restrict__ out, int M, int N, int K)
{
    __shared__ ushort As[2][64 * 32];
    __shared__ ushort Bs[2][64 * 32];
    int bm = blockIdx.x * 64, bn = blockIdx.y * 64;
    int tid = threadIdx.x;
    int wid = tid >> 6, lane = tid & 63;
    int wm = (wid >> 1) * 32, wn = (wid & 1) * 32;
    int lg = lane >> 4, lr = lane & 15;
    int srow = tid >> 2;
    int sunit = (tid & 3) ^ (srow & 3);
    f32x4 acc[2][2] = {};

    const ushort* ga = A  + (size_t)(bm + srow) * K + sunit * 8;
    const ushort* gb = Bt + (size_t)(bn + srow) * K + sunit * 8;

    gl_lds16(ga, &As[0][tid * 8]);
    gl_lds16(gb, &Bs[0][tid * 8]);

    int nt = K >> 5;
    for (int t = 0; t < nt; t++) {
        int cur = t & 1;
        __syncthreads();
        if (t + 1 < nt) {
            int k0 = (t + 1) << 5;
            int nb = cur ^ 1;
            gl_lds16(ga + k0, &As[nb][tid * 8]);
            gl_lds16(gb + k0, &Bs[nb][tid * 8]);
        }
        short8 a[2], b[2];
        #pragma unroll
        for (int mi = 0; mi < 2; mi++) {
            int row = wm + mi * 16 + lr;
            a[mi] = *(const short8*)&As[cur][row * 32 + ((lg ^ (row & 3)) * 8)];
        }
        #pragma unroll
        for (int ni = 0; ni < 2; ni++) {
            int row = wn + ni * 16 + lr;
            b[ni] = *(const short8*)&Bs[cur][row * 32 + ((lg ^ (row & 3)) * 8)];
        }
        #pragma unroll
        for (int mi = 0; mi < 2; mi++)
            #pragma unroll
            for (int ni = 0; ni < 2; ni++)
                acc[mi][ni] = __builtin_amdgcn_mfma_f32_16x16x32_bf16(a[mi], b[ni], acc[mi][ni], 0, 0, 0);
    }

    #pragma unroll
    for (int mi = 0; mi < 2; mi++) {
        #pragma unroll
        for (int ni = 0; ni < 2; ni++) {
            int col = bn + wn + ni * 16 + lr;
            float bv = bias[col];
            #pragma unroll
            for (int r = 0; r < 4; r++) {
                int row = bm + wm + mi * 16 + lg * 4 + r;
                float v = acc[mi][ni][r] + bv;
                size_t idx = (size_t)row * N + col;
                if (EPI == 0) {
                    ((ushort*)out)[idx] = f2bf(v);
                } else if (EPI == 1) {
                    ((ushort*)out)[idx] = f2bf(gelu_fast(v));
                } else {
                    ((float*)out)[idx] = v + res[idx];
                }
            }
        }
    }
}

// ---------------- flash attention (split-K x4, QBLK=256, 52KB LDS, XCD-local KV) ----------------
// Q pre-scaled by C1 in the QKV epilogue -> per-element softmax is a bare v_exp_f32.
__global__ __launch_bounds__(512) void attn_kernel(
    const ushort* __restrict__ qkv, const ushort* __restrict__ vT,
    ushort* __restrict__ Opart, float* __restrict__ ml)
{
    int combo = blockIdx.x % 48;
    int qblk  = blockIdx.x / 48;
    int h     = combo >> 2;
    int split = combo & 3;
    __shared__ ushort smem[16384 + 256 * 40];    // K/V dbuf (32KB) + P scratch (20KB)
    ushort* Ps = smem + 16384;
    int tid = threadIdx.x, wid = tid >> 6, lane = tid & 63;
    int lg = lane >> 4, lr = lane & 15;
    int x7 = lr & 7;

    { // stage Q: dest-XOR swizzled LDS, linear global source
        int row = tid >> 1;
        int u0 = (tid & 1) * 4;
        int r7 = row & 7;
        const ushort* src = qkv + (size_t)(qblk * 256 + row) * 2304 + h * HDIM;
        #pragma unroll
        for (int i = 0; i < 4; i++) {
            int u = u0 + i;
            *(short8*)&smem[row * 64 + ((u ^ r7) * 8)] = *(const short8*)(src + (size_t)(u * 8));
        }
    }
    int q0row = (wid * 32 + lr) * 64;
    int q1row = q0row + 16 * 64;
    short8 qa0 = *(const short8*)&smem[q0row + (lg ^ x7) * 8];
    short8 qa1 = *(const short8*)&smem[q0row + ((4 + lg) ^ x7) * 8];
    short8 qb0 = *(const short8*)&smem[q1row + (lg ^ x7) * 8];
    short8 qb1 = *(const short8*)&smem[q1row + ((4 + lg) ^ x7) * 8];
    __syncthreads();

    short8 vone;
    #pragma unroll
    for (int i = 0; i < 8; i++) vone[i] = (short)0x3F80;

    int krow = tid >> 3;
    int kunit = (tid & 7) ^ (krow & 7);
    const ushort* kg = qkv + (size_t)(split * 1024 + krow) * 2304 + DMODEL + h * HDIM + kunit * 8;
    const ushort* vgp = vT + (size_t)(h * HDIM + krow) * TSEQ + split * 1024 + kunit * 8;

    gl_lds16(kg, &smem[tid * 8]);
    gl_lds16(vgp, &smem[8192 + tid * 8]);
    kg += 64 * 2304;
    vgp += 64;

    f32x4 o0[4] = {}, o1[4] = {};
    f32x4 s0sum = {}, s1sum = {};
    const int NT = 16;
    int prow0 = (wid * 32 + lr) * 40;
    int prow1 = prow0 + 16 * 40;

    for (int kt = 0; kt < NT; kt++) {
        int cur = kt & 1, nb = cur ^ 1;
        __syncthreads();
        if (kt + 1 < NT) {
            gl_lds16(kg, &smem[nb * 4096 + tid * 8]);
            gl_lds16(vgp, &smem[8192 + nb * 4096 + tid * 8]);
            kg += 64 * 2304;
            vgp += 64;
        }
        const ushort* kb = &smem[cur * 4096];
        const ushort* vb = &smem[8192 + cur * 4096];

        f32x4 st0[4] = {}, st1[4] = {};
        __builtin_amdgcn_s_setprio(1);
        #pragma unroll
        for (int ki = 0; ki < 4; ki++) {
            const ushort* kr = &kb[(ki * 16 + lr) * 64];
            short8 k0 = *(const short8*)&kr[(lg ^ x7) * 8];
            short8 k1 = *(const short8*)&kr[((4 + lg) ^ x7) * 8];
            st0[ki] = __builtin_amdgcn_mfma_f32_16x16x32_bf16(k0, qa0, st0[ki], 0, 0, 0);
            st0[ki] = __builtin_amdgcn_mfma_f32_16x16x32_bf16(k1, qa1, st0[ki], 0, 0, 0);
            st1[ki] = __builtin_amdgcn_mfma_f32_16x16x32_bf16(k0, qb0, st1[ki], 0, 0, 0);
            st1[ki] = __builtin_amdgcn_mfma_f32_16x16x32_bf16(k1, qb1, st1[ki], 0, 0, 0);
        }
        __builtin_amdgcn_s_setprio(0);

        uint2 c0[4], c1[4];
        #pragma unroll
        for (int ki = 0; ki < 4; ki++) {
            #pragma unroll
            for (int r = 0; r < 4; r++) st0[ki][r] = exp2f(st0[ki][r]);
            asm("v_cvt_pk_bf16_f32 %0, %1, %2" : "=v"(c0[ki].x) : "v"(st0[ki][0]), "v"(st0[ki][1]));
            asm("v_cvt_pk_bf16_f32 %0, %1, %2" : "=v"(c0[ki].y) : "v"(st0[ki][2]), "v"(st0[ki][3]));
        }
        #pragma unroll
        for (int ki = 0; ki < 4; ki++) {
            #pragma unroll
            for (int r = 0; r < 4; r++) st1[ki][r] = exp2f(st1[ki][r]);
            asm("v_cvt_pk_bf16_f32 %0, %1, %2" : "=v"(c1[ki].x) : "v"(st1[ki][0]), "v"(st1[ki][1]));
            asm("v_cvt_pk_bf16_f32 %0, %1, %2" : "=v"(c1[ki].y) : "v"(st1[ki][2]), "v"(st1[ki][3]));
        }

        *(uint2*)&Ps[prow0 + lg * 4]      = c0[0];
        *(uint2*)&Ps[prow0 + 16 + lg * 4] = c0[1];
        *(uint2*)&Ps[prow1 + lg * 4]      = c1[0];
        *(uint2*)&Ps[prow1 + 16 + lg * 4] = c1[1];
        {
            short8 pa00 = *(const short8*)&Ps[prow0 + lg * 8];
            short8 pa10 = *(const short8*)&Ps[prow1 + lg * 8];
            __builtin_amdgcn_s_setprio(1);
            s0sum = __builtin_amdgcn_mfma_f32_16x16x32_bf16(pa00, vone, s0sum, 0, 0, 0);
            s1sum = __builtin_amdgcn_mfma_f32_16x16x32_bf16(pa10, vone, s1sum, 0, 0, 0);
            #pragma unroll
            for (int ni = 0; ni < 4; ni++) {
                short8 b0 = *(const short8*)&vb[(ni * 16 + lr) * 64 + (lg ^ x7) * 8];
                o0[ni] = __builtin_amdgcn_mfma_f32_16x16x32_bf16(pa00, b0, o0[ni], 0, 0, 0);
                o1[ni] = __builtin_amdgcn_mfma_f32_16x16x32_bf16(pa10, b0, o1[ni], 0, 0, 0);
            }
            __builtin_amdgcn_s_setprio(0);
        }
        *(uint2*)&Ps[prow0 + lg * 4]      = c0[2];
        *(uint2*)&Ps[prow0 + 16 + lg * 4] = c0[3];
        *(uint2*)&Ps[prow1 + lg * 4]      = c1[2];
        *(uint2*)&Ps[prow1 + 16 + lg * 4] = c1[3];
        {
            short8 pa01 = *(const short8*)&Ps[prow0 + lg * 8];
            short8 pa11 = *(const short8*)&Ps[prow1 + lg * 8];
            __builtin_amdgcn_s_setprio(1);
            s0sum = __builtin_amdgcn_mfma_f32_16x16x32_bf16(pa01, vone, s0sum, 0, 0, 0);
            s1sum = __builtin_amdgcn_mfma_f32_16x16x32_bf16(pa11, vone, s1sum, 0, 0, 0);
            #pragma unroll
            for (int ni = 0; ni < 4; ni++) {
                short8 b1 = *(const short8*)&vb[(ni * 16 + lr) * 64 + ((4 + lg) ^ x7) * 8];
                o0[ni] = __builtin_amdgcn_mfma_f32_16x16x32_bf16(pa01, b1, o0[ni], 0, 0, 0);
                o1[ni] = __builtin_amdgcn_mfma_f32_16x16x32_bf16(pa11, b1, o1[ni], 0, 0, 0);
            }
            __builtin_amdgcn_s_setprio(0);
        }
    }

    if (lr == 0) {
        #pragma unroll
        for (int r = 0; r < 4; r++) {
            int q0 = qblk * 256 + wid * 32 + lg * 4 + r;
            ml[((size_t)split * NHEADS + h) * TSEQ + q0]      = s0sum[r];
            ml[((size_t)split * NHEADS + h) * TSEQ + q0 + 16] = s1sum[r];
        }
    }
    #pragma unroll
    for (int ni = 0; ni < 4; ni++)
        #pragma unroll
        for (int r = 0; r < 4; r++) {
            int q0 = qblk * 256 + wid * 32 + lg * 4 + r;
            int dcol = ni * 16 + lr;
            Opart[((size_t)split * TSEQ + q0) * DMODEL + h * HDIM + dcol]      = f2bf(o0[ni][r]);
            Opart[((size_t)split * TSEQ + q0 + 16) * DMODEL + h * HDIM + dcol] = f2bf(o1[ni][r]);
        }
}

// ---------------- combine 4 split partials -> attn bf16 (8 elems/thread, uint4 I/O) ----------------
__global__ __launch_bounds__(256) void attn_combine_kernel(
    const ushort* __restrict__ Opart, const float* __restrict__ ml,
    ushort* __restrict__ attnb)
{
    int gid = blockIdx.x * 256 + threadIdx.x;     // T*768/8 total
    int q = gid / 96;
    int c = (gid - q * 96) * 8;
    int hh = c >> 6;
    float denom = 0.f;
    float a[8] = {};
    #pragma unroll
    for (int s = 0; s < 4; s++) {
        denom += ml[((size_t)s * NHEADS + hh) * TSEQ + q];
        uint4 ov = *(const uint4*)&Opart[((size_t)s * TSEQ + q) * DMODEL + c];
        uint w0 = ov.x, w1 = ov.y, w2 = ov.z, w3 = ov.w;
        a[0] += asf(w0 << 16); a[1] += asf(w0 & 0xFFFF0000u);
        a[2] += asf(w1 << 16); a[3] += asf(w1 & 0xFFFF0000u);
        a[4] += asf(w2 << 16); a[5] += asf(w2 & 0xFFFF0000u);
        a[6] += asf(w3 << 16); a[7] += asf(w3 & 0xFFFF0000u);
    }
    float rd = 1.f / denom;
    uint4 stv;
    stv.x = (uint)f2bf(a[0] * rd) | ((uint)f2bf(a[1] * rd) << 16);
    stv.y = (uint)f2bf(a[2] * rd) | ((uint)f2bf(a[3] * rd) << 16);
    stv.z = (uint)f2bf(a[4] * rd) | ((uint)f2bf(a[5] * rd) << 16);
    stv.w = (uint)f2bf(a[6] * rd) | ((uint)f2bf(a[7] * rd) << 16);
    *(uint4*)&attnb[(size_t)q * DMODEL + c] = stv;
}

// ---------------- host launch ----------------
extern "C" void kernel_launch(void* const* d_in, const int* in_sizes, int n_in,
                              void* d_out, int out_size, void* d_ws, size_t ws_size,
                              hipStream_t stream)
{
    const float* x      = (const float*)d_in[0];
    const float* ln1_g  = (const float*)d_in[1];
    const float* ln1_b  = (const float*)d_in[2];
    const float* ln2_g  = (const float*)d_in[3];
    const float* ln2_b  = (const float*)d_in[4];
    const float* qkv_w  = (const float*)d_in[5];
    const float* qkv_b  = (const float*)d_in[6];
    const float* out_w  = (const float*)d_in[7];
    const float* out_b  = (const float*)d_in[8];
    const float* fc1_w  = (const float*)d_in[9];
    const float* fc1_b  = (const float*)d_in[10];
    const float* fc2_w  = (const float*)d_in[11];
    const float* fc2_b  = (const float*)d_in[12];
    (void)in_sizes; (void)n_in; (void)out_size; (void)ws_size;

    char* p = (char*)d_ws;
    ushort* qkvb  = (ushort*)p;                 p += (size_t)TSEQ * DFF * 2;          // also gelu-out
    ushort* hb    = (ushort*)p;                 p += (size_t)TSEQ * DMODEL * 2;
    ushort* attnb = (ushort*)p;                 p += (size_t)TSEQ * DMODEL * 2;
    float*  x2    = (float*)p;                  p += (size_t)TSEQ * DMODEL * 4;
    ushort* qkv_wT = (ushort*)p;                p += (size_t)(3 * DMODEL) * DMODEL * 2;
    ushort* out_wT = (ushort*)p;                p += (size_t)DMODEL * DMODEL * 2;
    ushort* fc1_wT = (ushort*)p;                p += (size_t)DFF * DMODEL * 2;
    ushort* fc2_wT = (ushort*)p;                p += (size_t)DMODEL * DFF * 2;
    ushort* Opart  = (ushort*)p;                p += (size_t)4 * TSEQ * DMODEL * 2;
    float*  mlbuf  = (float*)p;                 p += (size_t)4 * NHEADS * TSEQ * 4;
    ushort* vTb    = (ushort*)p;                p += (size_t)DMODEL * TSEQ * 2;
    ushort* gb = qkvb;

    // weights transpose + LN1 in one launch
    prep_kernel<<<11008, 256, 0, stream>>>(
        qkv_w, out_w, fc1_w, fc2_w, x, ln1_g, ln1_b,
        qkv_wT, out_wT, fc1_wT, fc2_wT, hb);

    gemm_kernel<3><<<dim3(TSEQ / 128, 3 * DMODEL / 128), 256, 0, stream>>>(
        hb, qkv_wT, qkv_b, nullptr, qkvb, vTb, TSEQ, 3 * DMODEL, DMODEL);
    attn_kernel<<<dim3((TSEQ / 256) * NHEADS * 4), 512, 0, stream>>>(qkvb, vTb, Opart, mlbuf);
    attn_combine_kernel<<<(TSEQ * DMODEL / 8) / 256, 256, 0, stream>>>(Opart, mlbuf, attnb);
    gemm_64_kernel<2><<<dim3(TSEQ / 64, DMODEL / 64), 256, 0, stream>>>(
        attnb, out_wT, out_b, x, x2, TSEQ, DMODEL, DMODEL);
    ln_half_kernel<<<TSEQ, 256, 0, stream>>>(x2, ln2_g, ln2_b, hb);
    gemm_kernel<1><<<dim3(TSEQ / 128, DFF / 128), 256, 0, stream>>>(
        hb, fc1_wT, fc1_b, nullptr, gb, nullptr, TSEQ, DFF, DMODEL);
    gemm_64_kernel<2><<<dim3(TSEQ / 64, DMODEL / 64), 256, 0, stream>>>(
        gb, fc2_wT, fc2_b, x2, (float*)d_out, TSEQ, DMODEL, DFF);
}

// Round 21
// 194.905 us; speedup vs baseline: 1.1453x; 1.0300x over previous
//
#include <hip/hip_runtime.h>
#include <hip/hip_bf16.h>
#include <math.h>

#define TSEQ 4096
#define DMODEL 768
#define DFF 3072
#define NHEADS 12
#define HDIM 64

typedef __attribute__((ext_vector_type(8))) short short8;
typedef __attribute__((ext_vector_type(4))) float f32x4;
typedef unsigned short ushort;
typedef unsigned int uint;

typedef __attribute__((address_space(1))) ushort as1_ushort;
typedef __attribute__((address_space(3))) ushort as3_ushort;

__device__ __forceinline__ void gl_lds16(const ushort* g, const ushort* l) {
    __builtin_amdgcn_global_load_lds((as1_ushort*)(uintptr_t)g,
                                     (as3_ushort*)(uint)(uintptr_t)l, 16, 0, 0);
}

__device__ __forceinline__ ushort f2bf(float f) {
    union { float f; unsigned i; } c; c.f = f;
    unsigned x = c.i;
    unsigned r = x + 0x7FFFu + ((x >> 16) & 1u);
    return (ushort)(r >> 16);
}
__device__ __forceinline__ float asf(uint u) {
    union { unsigned i; float f; } c; c.i = u; return c.f;
}
// tanh-form GELU
__device__ __forceinline__ float gelu_fast(float v) {
    float y = v * (0.7978845608f + 0.03567740814f * v * v);
    float u = exp2f(y * -2.8853900817779268f);
    float r;
    asm("v_rcp_f32 %0, %1" : "=v"(r) : "v"(1.f + u));
    return v * r;
}

// ---------------- LayerNorm * 0.5 -> bf16 (ln2 only; ln1 fused into prep) ----------------
__global__ __launch_bounds__(256) void ln_half_kernel(
    const float* __restrict__ x, const float* __restrict__ g,
    const float* __restrict__ b, ushort* __restrict__ out)
{
    int row = blockIdx.x;
    const float* xr = x + (size_t)row * DMODEL;
    float v[3];
    float s = 0.f, s2 = 0.f;
    #pragma unroll
    for (int i = 0; i < 3; i++) {
        v[i] = xr[threadIdx.x + 256 * i];
        s += v[i]; s2 += v[i] * v[i];
    }
    #pragma unroll
    for (int m = 1; m < 64; m <<= 1) { s += __shfl_xor(s, m, 64); s2 += __shfl_xor(s2, m, 64); }
    __shared__ float ss[4], ss2[4];
    int wid = threadIdx.x >> 6;
    if ((threadIdx.x & 63) == 0) { ss[wid] = s; ss2[wid] = s2; }
    __syncthreads();
    s = ss[0] + ss[1] + ss[2] + ss[3];
    s2 = ss2[0] + ss2[1] + ss2[2] + ss2[3];
    float mu = s * (1.f / DMODEL);
    float var = s2 * (1.f / DMODEL) - mu * mu;
    float rs = rsqrtf(var + 1e-5f);
    #pragma unroll
    for (int i = 0; i < 3; i++) {
        int c = threadIdx.x + 256 * i;
        float h = (v[i] - mu) * rs * g[c] + b[c];
        out[(size_t)row * DMODEL + c] = f2bf(h * 0.5f);
    }
}

// ---------------- prep: all 4 weight transposes + LN1, one launch ----------------
__global__ __launch_bounds__(256) void prep_kernel(
    const float* __restrict__ qkv_w, const float* __restrict__ out_w,
    const float* __restrict__ fc1_w, const float* __restrict__ fc2_w,
    const float* __restrict__ x, const float* __restrict__ ln1_g,
    const float* __restrict__ ln1_b,
    ushort* __restrict__ qkv_wT, ushort* __restrict__ out_wT,
    ushort* __restrict__ fc1_wT, ushort* __restrict__ fc2_wT,
    ushort* __restrict__ hb)
{
    __shared__ float tile[32][33];
    int bid = blockIdx.x;
    if (bid >= 6912) {
        int row = bid - 6912;
        const float* xr = x + (size_t)row * DMODEL;
        float v[3];
        float s = 0.f, s2 = 0.f;
        #pragma unroll
        for (int i = 0; i < 3; i++) {
            v[i] = xr[threadIdx.x + 256 * i];
            s += v[i]; s2 += v[i] * v[i];
        }
        #pragma unroll
        for (int m = 1; m < 64; m <<= 1) { s += __shfl_xor(s, m, 64); s2 += __shfl_xor(s2, m, 64); }
        float* ss = (float*)tile;
        int wid = threadIdx.x >> 6;
        if ((threadIdx.x & 63) == 0) { ss[wid] = s; ss[4 + wid] = s2; }
        __syncthreads();
        s = ss[0] + ss[1] + ss[2] + ss[3];
        s2 = ss[4] + ss[5] + ss[6] + ss[7];
        float mu = s * (1.f / DMODEL);
        float var = s2 * (1.f / DMODEL) - mu * mu;
        float rs = rsqrtf(var + 1e-5f);
        #pragma unroll
        for (int i = 0; i < 3; i++) {
            int c = threadIdx.x + 256 * i;
            float h = (v[i] - mu) * rs * ln1_g[c] + ln1_b[c];
            hb[(size_t)row * DMODEL + c] = f2bf(h * 0.5f);
        }
        return;
    }
    const float* in; ushort* out; int K, N, tile_id;
    if (bid < 1728)      { in = qkv_w; out = qkv_wT; K = 768;  N = 2304; tile_id = bid; }
    else if (bid < 2304) { in = out_w; out = out_wT; K = 768;  N = 768;  tile_id = bid - 1728; }
    else if (bid < 4608) { in = fc1_w; out = fc1_wT; K = 768;  N = 3072; tile_id = bid - 2304; }
    else                 { in = fc2_w; out = fc2_wT; K = 3072; N = 768;  tile_id = bid - 4608; }
    int nx = K >> 5;
    int k0 = (tile_id % nx) * 32, n0 = (tile_id / nx) * 32;

    int c = threadIdx.x & 31, r0 = threadIdx.x >> 5;
    #pragma unroll
    for (int i = 0; i < 4; i++) {
        int r = r0 + i * 8;
        tile[r][c] = in[(size_t)(k0 + r) * N + n0 + c];
    }
    __syncthreads();
    #pragma unroll
    for (int i = 0; i < 4; i++) {
        int r = r0 + i * 8;
        out[(size_t)(n0 + r) * K + k0 + c] = f2bf(tile[c][r]);
    }
}

// ---------------- GEMM BN=128 (EPI 0: bias->bf16; 1: bias+GELU->bf16; 2: bias+res->f32;
//   3: QKV fused — Q cols (bn<768) pre-scaled by C1; V cols (bn>=1536) -> vTout transposed)
template<int EPI>
__global__ __launch_bounds__(256) void gemm_kernel(
    const ushort* __restrict__ A, const ushort* __restrict__ Bt,
    const float* __restrict__ bias, const float* __restrict__ res,
    void* __restrict__ out, ushort* __restrict__ vTout, int M, int N, int K)
{
    __shared__ ushort As[2][128 * 32];
    __shared__ ushort Bs[2][128 * 32];
    int bm = blockIdx.x * 128, bn = blockIdx.y * 128;
    int tid = threadIdx.x;
    int wid = tid >> 6, lane = tid & 63;
    int wm = (wid >> 1) * 64, wn = (wid & 1) * 64;
    int lg = lane >> 4, lr = lane & 15;
    int srow = lane >> 2, scol = (lane & 3) * 8;
    f32x4 acc[4][4] = {};

    const ushort* ga0 = A  + (size_t)(bm + wid * 16 + srow) * K + scol;
    const ushort* ga1 = A  + (size_t)(bm + 64 + wid * 16 + srow) * K + scol;
    const ushort* gb0 = Bt + (size_t)(bn + wid * 16 + srow) * K + scol;
    const ushort* gb1 = Bt + (size_t)(bn + 64 + wid * 16 + srow) * K + scol;

    gl_lds16(ga0, &As[0][wid * 512]);
    gl_lds16(ga1, &As[0][2048 + wid * 512]);
    gl_lds16(gb0, &Bs[0][wid * 512]);
    gl_lds16(gb1, &Bs[0][2048 + wid * 512]);

    int nt = K >> 5;
    for (int t = 0; t < nt; t++) {
        int cur = t & 1;
        __syncthreads();
        if (t + 1 < nt) {
            int k0 = (t + 1) << 5;
            int nb = cur ^ 1;
            gl_lds16(ga0 + k0, &As[nb][wid * 512]);
            gl_lds16(ga1 + k0, &As[nb][2048 + wid * 512]);
            gl_lds16(gb0 + k0, &Bs[nb][wid * 512]);
            gl_lds16(gb1 + k0, &Bs[nb][2048 + wid * 512]);
        }
        short8 a[4], b[4];
        #pragma unroll
        for (int mi = 0; mi < 4; mi++) a[mi] = *(const short8*)&As[cur][(wm + mi * 16 + lr) * 32 + lg * 8];
        #pragma unroll
        for (int ni = 0; ni < 4; ni++) b[ni] = *(const short8*)&Bs[cur][(wn + ni * 16 + lr) * 32 + lg * 8];
        #pragma unroll
        for (int mi = 0; mi < 4; mi++)
            #pragma unroll
            for (int ni = 0; ni < 4; ni++)
                acc[mi][ni] = __builtin_amdgcn_mfma_f32_16x16x32_bf16(a[mi], b[ni], acc[mi][ni], 0, 0, 0);
    }

    const float C1 = 0.18033688011112042f;
    #pragma unroll
    for (int mi = 0; mi < 4; mi++) {
        #pragma unroll
        for (int ni = 0; ni < 4; ni++) {
            int col = bn + wn + ni * 16 + lr;
            float bv = bias[col];
            if (EPI == 3 && bn >= 1536) {
                int row0 = bm + wm + mi * 16 + lg * 4;
                uint2 pk;
                pk.x = (uint)f2bf(acc[mi][ni][0] + bv) | ((uint)f2bf(acc[mi][ni][1] + bv) << 16);
                pk.y = (uint)f2bf(acc[mi][ni][2] + bv) | ((uint)f2bf(acc[mi][ni][3] + bv) << 16);
                *(uint2*)&vTout[(size_t)(col - 1536) * TSEQ + row0] = pk;
            } else {
                #pragma unroll
                for (int r = 0; r < 4; r++) {
                    int row = bm + wm + mi * 16 + lg * 4 + r;
                    float v = acc[mi][ni][r] + bv;
                    size_t idx = (size_t)row * N + col;
                    if (EPI == 1) {
                        ((ushort*)out)[idx] = f2bf(gelu_fast(v));
                    } else if (EPI == 2) {
                        ((float*)out)[idx] = v + res[idx];
                    } else if (EPI == 3) {
                        ((ushort*)out)[idx] = f2bf(bn < 768 ? v * C1 : v);
                    } else {
                        ((ushort*)out)[idx] = f2bf(v);
                    }
                }
            }
        }
    }
}

// ---------------- GEMM 64x64, BK=64 (skinny-N: out-proj, FC2) ----------------
// 8 MFMA + 4 gl_lds per barrier (2x the BK=32 amortization). LDS 32KB.
// Staging: call j covers rows 32j + (tid>>3), unit (tid&7)^(row&7) (32 = 0 mod 8).
template<int EPI>
__global__ __launch_bounds__(256) void gemm_64_kernel(
    const ushort* __restrict__ A, const ushort* __restrict__ Bt,
    const float* __restrict__ bias, const float* __restrict__ res,
    void* __restrict__ out, int M, int N, int K)
{
    __shared__ ushort As[2][64 * 64];
    __shared__ ushort Bs[2][64 * 64];
    int bm = blockIdx.x * 64, bn = blockIdx.y * 64;
    int tid = threadIdx.x;
    int wid = tid >> 6, lane = tid & 63;
    int wm = (wid >> 1) * 32, wn = (wid & 1) * 32;
    int lg = lane >> 4, lr = lane & 15;
    int srow = tid >> 3;                 // 0..31
    int sunit = (tid & 7) ^ (srow & 7);
    f32x4 acc[2][2] = {};

    const ushort* ga0 = A  + (size_t)(bm + srow) * K + sunit * 8;
    const ushort* ga1 = A  + (size_t)(bm + 32 + srow) * K + sunit * 8;
    const ushort* gb0 = Bt + (size_t)(bn + srow) * K + sunit * 8;
    const ushort* gb1 = Bt + (size_t)(bn + 32 + srow) * K + sunit * 8;

    gl_lds16(ga0, &As[0][tid * 8]);
    gl_lds16(ga1, &As[0][2048 + tid * 8]);
    gl_lds16(gb0, &Bs[0][tid * 8]);
    gl_lds16(gb1, &Bs[0][2048 + tid * 8]);

    int nt = K >> 6;
    for (int t = 0; t < nt; t++) {
        int cur = t & 1;
        __syncthreads();
        if (t + 1 < nt) {
            int k0 = (t + 1) << 6;
            int nb = cur ^ 1;
            gl_lds16(ga0 + k0, &As[nb][tid * 8]);
            gl_lds16(ga1 + k0, &As[nb][2048 + tid * 8]);
            gl_lds16(gb0 + k0, &Bs[nb][tid * 8]);
            gl_lds16(gb1 + k0, &Bs[nb][2048 + tid * 8]);
        }
        #pragma unroll
        for (int h = 0; h < 2; h++) {
            short8 a[2], b[2];
            #pragma unroll
            for (int mi = 0; mi < 2; mi++) {
                int row = wm + mi * 16 + lr;
                a[mi] = *(const short8*)&As[cur][row * 64 + (((h * 4 + lg) ^ (row & 7)) * 8)];
            }
            #pragma unroll
            for (int ni = 0; ni < 2; ni++) {
                int row = wn + ni * 16 + lr;
                b[ni] = *(const short8*)&Bs[cur][row * 64 + (((h * 4 + lg) ^ (row & 7)) * 8)];
            }
            #pragma unroll
            for (int mi = 0; mi < 2; mi++)
                #pragma unroll
                for (int ni = 0; ni < 2; ni++)
                    acc[mi][ni] = __builtin_amdgcn_mfma_f32_16x16x32_bf16(a[mi], b[ni], acc[mi][ni], 0, 0, 0);
        }
    }

    #pragma unroll
    for (int mi = 0; mi < 2; mi++) {
        #pragma unroll
        for (int ni = 0; ni < 2; ni++) {
            int col = bn + wn + ni * 16 + lr;
            float bv = bias[col];
            #pragma unroll
            for (int r = 0; r < 4; r++) {
                int row = bm + wm + mi * 16 + lg * 4 + r;
                float v = acc[mi][ni][r] + bv;
                size_t idx = (size_t)row * N + col;
                if (EPI == 0) {
                    ((ushort*)out)[idx] = f2bf(v);
                } else if (EPI == 1) {
                    ((ushort*)out)[idx] = f2bf(gelu_fast(v));
                } else {
                    ((float*)out)[idx] = v + res[idx];
                }
            }
        }
    }
}

// ---------------- flash attention (split-K x4, QBLK=256, 52KB LDS, XCD-local KV) ----------------
// Q pre-scaled by C1 in the QKV epilogue -> per-element softmax is a bare v_exp_f32.
__global__ __launch_bounds__(512) void attn_kernel(
    const ushort* __restrict__ qkv, const ushort* __restrict__ vT,
    ushort* __restrict__ Opart, float* __restrict__ ml)
{
    int combo = blockIdx.x % 48;
    int qblk  = blockIdx.x / 48;
    int h     = combo >> 2;
    int split = combo & 3;
    __shared__ ushort smem[16384 + 256 * 40];    // K/V dbuf (32KB) + P scratch (20KB)
    ushort* Ps = smem + 16384;
    int tid = threadIdx.x, wid = tid >> 6, lane = tid & 63;
    int lg = lane >> 4, lr = lane & 15;
    int x7 = lr & 7;

    { // stage Q: dest-XOR swizzled LDS, linear global source
        int row = tid >> 1;
        int u0 = (tid & 1) * 4;
        int r7 = row & 7;
        const ushort* src = qkv + (size_t)(qblk * 256 + row) * 2304 + h * HDIM;
        #pragma unroll
        for (int i = 0; i < 4; i++) {
            int u = u0 + i;
            *(short8*)&smem[row * 64 + ((u ^ r7) * 8)] = *(const short8*)(src + (size_t)(u * 8));
        }
    }
    int q0row = (wid * 32 + lr) * 64;
    int q1row = q0row + 16 * 64;
    short8 qa0 = *(const short8*)&smem[q0row + (lg ^ x7) * 8];
    short8 qa1 = *(const short8*)&smem[q0row + ((4 + lg) ^ x7) * 8];
    short8 qb0 = *(const short8*)&smem[q1row + (lg ^ x7) * 8];
    short8 qb1 = *(const short8*)&smem[q1row + ((4 + lg) ^ x7) * 8];
    __syncthreads();

    short8 vone;
    #pragma unroll
    for (int i = 0; i < 8; i++) vone[i] = (short)0x3F80;

    int krow = tid >> 3;
    int kunit = (tid & 7) ^ (krow & 7);
    const ushort* kg = qkv + (size_t)(split * 1024 + krow) * 2304 + DMODEL + h * HDIM + kunit * 8;
    const ushort* vgp = vT + (size_t)(h * HDIM + krow) * TSEQ + split * 1024 + kunit * 8;

    gl_lds16(kg, &smem[tid * 8]);
    gl_lds16(vgp, &smem[8192 + tid * 8]);
    kg += 64 * 2304;
    vgp += 64;

    f32x4 o0[4] = {}, o1[4] = {};
    f32x4 s0sum = {}, s1sum = {};
    const int NT = 16;
    int prow0 = (wid * 32 + lr) * 40;
    int prow1 = prow0 + 16 * 40;

    for (int kt = 0; kt < NT; kt++) {
        int cur = kt & 1, nb = cur ^ 1;
        __syncthreads();
        if (kt + 1 < NT) {
            gl_lds16(kg, &smem[nb * 4096 + tid * 8]);
            gl_lds16(vgp, &smem[8192 + nb * 4096 + tid * 8]);
            kg += 64 * 2304;
            vgp += 64;
        }
        const ushort* kb = &smem[cur * 4096];
        const ushort* vb = &smem[8192 + cur * 4096];

        f32x4 st0[4] = {}, st1[4] = {};
        __builtin_amdgcn_s_setprio(1);
        #pragma unroll
        for (int ki = 0; ki < 4; ki++) {
            const ushort* kr = &kb[(ki * 16 + lr) * 64];
            short8 k0 = *(const short8*)&kr[(lg ^ x7) * 8];
            short8 k1 = *(const short8*)&kr[((4 + lg) ^ x7) * 8];
            st0[ki] = __builtin_amdgcn_mfma_f32_16x16x32_bf16(k0, qa0, st0[ki], 0, 0, 0);
            st0[ki] = __builtin_amdgcn_mfma_f32_16x16x32_bf16(k1, qa1, st0[ki], 0, 0, 0);
            st1[ki] = __builtin_amdgcn_mfma_f32_16x16x32_bf16(k0, qb0, st1[ki], 0, 0, 0);
            st1[ki] = __builtin_amdgcn_mfma_f32_16x16x32_bf16(k1, qb1, st1[ki], 0, 0, 0);
        }
        __builtin_amdgcn_s_setprio(0);

        uint2 c0[4], c1[4];
        #pragma unroll
        for (int ki = 0; ki < 4; ki++) {
            #pragma unroll
            for (int r = 0; r < 4; r++) st0[ki][r] = exp2f(st0[ki][r]);
            asm("v_cvt_pk_bf16_f32 %0, %1, %2" : "=v"(c0[ki].x) : "v"(st0[ki][0]), "v"(st0[ki][1]));
            asm("v_cvt_pk_bf16_f32 %0, %1, %2" : "=v"(c0[ki].y) : "v"(st0[ki][2]), "v"(st0[ki][3]));
        }
        #pragma unroll
        for (int ki = 0; ki < 4; ki++) {
            #pragma unroll
            for (int r = 0; r < 4; r++) st1[ki][r] = exp2f(st1[ki][r]);
            asm("v_cvt_pk_bf16_f32 %0, %1, %2" : "=v"(c1[ki].x) : "v"(st1[ki][0]), "v"(st1[ki][1]));
            asm("v_cvt_pk_bf16_f32 %0, %1, %2" : "=v"(c1[ki].y) : "v"(st1[ki][2]), "v"(st1[ki][3]));
        }

        *(uint2*)&Ps[prow0 + lg * 4]      = c0[0];
        *(uint2*)&Ps[prow0 + 16 + lg * 4] = c0[1];
        *(uint2*)&Ps[prow1 + lg * 4]      = c1[0];
        *(uint2*)&Ps[prow1 + 16 + lg * 4] = c1[1];
        {
            short8 pa00 = *(const short8*)&Ps[prow0 + lg * 8];
            short8 pa10 = *(const short8*)&Ps[prow1 + lg * 8];
            __builtin_amdgcn_s_setprio(1);
            s0sum = __builtin_amdgcn_mfma_f32_16x16x32_bf16(pa00, vone, s0sum, 0, 0, 0);
            s1sum = __builtin_amdgcn_mfma_f32_16x16x32_bf16(pa10, vone, s1sum, 0, 0, 0);
            #pragma unroll
            for (int ni = 0; ni < 4; ni++) {
                short8 b0 = *(const short8*)&vb[(ni * 16 + lr) * 64 + (lg ^ x7) * 8];
                o0[ni] = __builtin_amdgcn_mfma_f32_16x16x32_bf16(pa00, b0, o0[ni], 0, 0, 0);
                o1[ni] = __builtin_amdgcn_mfma_f32_16x16x32_bf16(pa10, b0, o1[ni], 0, 0, 0);
            }
            __builtin_amdgcn_s_setprio(0);
        }
        *(uint2*)&Ps[prow0 + lg * 4]      = c0[2];
        *(uint2*)&Ps[prow0 + 16 + lg * 4] = c0[3];
        *(uint2*)&Ps[prow1 + lg * 4]      = c1[2];
        *(uint2*)&Ps[prow1 + 16 + lg * 4] = c1[3];
        {
            short8 pa01 = *(const short8*)&Ps[prow0 + lg * 8];
            short8 pa11 = *(const short8*)&Ps[prow1 + lg * 8];
            __builtin_amdgcn_s_setprio(1);
            s0sum = __builtin_amdgcn_mfma_f32_16x16x32_bf16(pa01, vone, s0sum, 0, 0, 0);
            s1sum = __builtin_amdgcn_mfma_f32_16x16x32_bf16(pa11, vone, s1sum, 0, 0, 0);
            #pragma unroll
            for (int ni = 0; ni < 4; ni++) {
                short8 b1 = *(const short8*)&vb[(ni * 16 + lr) * 64 + ((4 + lg) ^ x7) * 8];
                o0[ni] = __builtin_amdgcn_mfma_f32_16x16x32_bf16(pa01, b1, o0[ni], 0, 0, 0);
                o1[ni] = __builtin_amdgcn_mfma_f32_16x16x32_bf16(pa11, b1, o1[ni], 0, 0, 0);
            }
            __builtin_amdgcn_s_setprio(0);
        }
    }

    if (lr == 0) {
        #pragma unroll
        for (int r = 0; r < 4; r++) {
            int q0 = qblk * 256 + wid * 32 + lg * 4 + r;
            ml[((size_t)split * NHEADS + h) * TSEQ + q0]      = s0sum[r];
            ml[((size_t)split * NHEADS + h) * TSEQ + q0 + 16] = s1sum[r];
        }
    }
    #pragma unroll
    for (int ni = 0; ni < 4; ni++)
        #pragma unroll
        for (int r = 0; r < 4; r++) {
            int q0 = qblk * 256 + wid * 32 + lg * 4 + r;
            int dcol = ni * 16 + lr;
            Opart[((size_t)split * TSEQ + q0) * DMODEL + h * HDIM + dcol]      = f2bf(o0[ni][r]);
            Opart[((size_t)split * TSEQ + q0 + 16) * DMODEL + h * HDIM + dcol] = f2bf(o1[ni][r]);
        }
}

// ---------------- combine 4 split partials -> attn bf16 (8 elems/thread, uint4 I/O) ----------------
__global__ __launch_bounds__(256) void attn_combine_kernel(
    const ushort* __restrict__ Opart, const float* __restrict__ ml,
    ushort* __restrict__ attnb)
{
    int gid = blockIdx.x * 256 + threadIdx.x;     // T*768/8 total
    int q = gid / 96;
    int c = (gid - q * 96) * 8;
    int hh = c >> 6;
    float denom = 0.f;
    float a[8] = {};
    #pragma unroll
    for (int s = 0; s < 4; s++) {
        denom += ml[((size_t)s * NHEADS + hh) * TSEQ + q];
        uint4 ov = *(const uint4*)&Opart[((size_t)s * TSEQ + q) * DMODEL + c];
        uint w0 = ov.x, w1 = ov.y, w2 = ov.z, w3 = ov.w;
        a[0] += asf(w0 << 16); a[1] += asf(w0 & 0xFFFF0000u);
        a[2] += asf(w1 << 16); a[3] += asf(w1 & 0xFFFF0000u);
        a[4] += asf(w2 << 16); a[5] += asf(w2 & 0xFFFF0000u);
        a[6] += asf(w3 << 16); a[7] += asf(w3 & 0xFFFF0000u);
    }
    float rd = 1.f / denom;
    uint4 stv;
    stv.x = (uint)f2bf(a[0] * rd) | ((uint)f2bf(a[1] * rd) << 16);
    stv.y = (uint)f2bf(a[2] * rd) | ((uint)f2bf(a[3] * rd) << 16);
    stv.z = (uint)f2bf(a[4] * rd) | ((uint)f2bf(a[5] * rd) << 16);
    stv.w = (uint)f2bf(a[6] * rd) | ((uint)f2bf(a[7] * rd) << 16);
    *(uint4*)&attnb[(size_t)q * DMODEL + c] = stv;
}

// ---------------- host launch ----------------
extern "C" void kernel_launch(void* const* d_in, const int* in_sizes, int n_in,
                              void* d_out, int out_size, void* d_ws, size_t ws_size,
                              hipStream_t stream)
{
    const float* x      = (const float*)d_in[0];
    const float* ln1_g  = (const float*)d_in[1];
    const float* ln1_b  = (const float*)d_in[2];
    const float* ln2_g  = (const float*)d_in[3];
    const float* ln2_b  = (const float*)d_in[4];
    const float* qkv_w  = (const float*)d_in[5];
    const float* qkv_b  = (const float*)d_in[6];
    const float* out_w  = (const float*)d_in[7];
    const float* out_b  = (const float*)d_in[8];
    const float* fc1_w  = (const float*)d_in[9];
    const float* fc1_b  = (const float*)d_in[10];
    const float* fc2_w  = (const float*)d_in[11];
    const float* fc2_b  = (const float*)d_in[12];
    (void)in_sizes; (void)n_in; (void)out_size; (void)ws_size;

    char* p = (char*)d_ws;
    ushort* qkvb  = (ushort*)p;                 p += (size_t)TSEQ * DFF * 2;          // also gelu-out
    ushort* hb    = (ushort*)p;                 p += (size_t)TSEQ * DMODEL * 2;
    ushort* attnb = (ushort*)p;                 p += (size_t)TSEQ * DMODEL * 2;
    float*  x2    = (float*)p;                  p += (size_t)TSEQ * DMODEL * 4;
    ushort* qkv_wT = (ushort*)p;                p += (size_t)(3 * DMODEL) * DMODEL * 2;
    ushort* out_wT = (ushort*)p;                p += (size_t)DMODEL * DMODEL * 2;
    ushort* fc1_wT = (ushort*)p;                p += (size_t)DFF * DMODEL * 2;
    ushort* fc2_wT = (ushort*)p;                p += (size_t)DMODEL * DFF * 2;
    ushort* Opart  = (ushort*)p;                p += (size_t)4 * TSEQ * DMODEL * 2;
    float*  mlbuf  = (float*)p;                 p += (size_t)4 * NHEADS * TSEQ * 4;
    ushort* vTb    = (ushort*)p;                p += (size_t)DMODEL * TSEQ * 2;
    ushort* gb = qkvb;

    prep_kernel<<<11008, 256, 0, stream>>>(
        qkv_w, out_w, fc1_w, fc2_w, x, ln1_g, ln1_b,
        qkv_wT, out_wT, fc1_wT, fc2_wT, hb);

    gemm_kernel<3><<<dim3(TSEQ / 128, 3 * DMODEL / 128), 256, 0, stream>>>(
        hb, qkv_wT, qkv_b, nullptr, qkvb, vTb, TSEQ, 3 * DMODEL, DMODEL);
    attn_kernel<<<dim3((TSEQ / 256) * NHEADS * 4), 512, 0, stream>>>(qkvb, vTb, Opart, mlbuf);
    attn_combine_kernel<<<(TSEQ * DMODEL / 8) / 256, 256, 0, stream>>>(Opart, mlbuf, attnb);
    gemm_64_kernel<2><<<dim3(TSEQ / 64, DMODEL / 64), 256, 0, stream>>>(
        attnb, out_wT, out_b, x, x2, TSEQ, DMODEL, DMODEL);
    ln_half_kernel<<<TSEQ, 256, 0, stream>>>(x2, ln2_g, ln2_b, hb);
    gemm_kernel<1><<<dim3(TSEQ / 128, DFF / 128), 256, 0, stream>>>(
        hb, fc1_wT, fc1_b, nullptr, gb, nullptr, TSEQ, DFF, DMODEL);
    gemm_64_kernel<2><<<dim3(TSEQ / 64, DMODEL / 64), 256, 0, stream>>>(
        gb, fc2_wT, fc2_b, x2, (float*)d_out, TSEQ, DMODEL, DFF);
}